// Round 1
// baseline (8612.699 us; speedup 1.0000x reference)
//
#include <hip/hip_runtime.h>
#include <hip/hip_bf16.h>

#define HID 128
#define NEG_SLOPE 0.2f

// ---------- helpers ----------
__device__ __forceinline__ unsigned fenc(float f) {
    unsigned u = __float_as_uint(f);
    return u ^ ((u >> 31) ? 0xFFFFFFFFu : 0x80000000u);
}
__device__ __forceinline__ float fdec(unsigned u) {
    unsigned v = (u & 0x80000000u) ? (u ^ 0x80000000u) : ~u;
    return __uint_as_float(v);
}

// ---------- kernels ----------

// One block (128 threads) per node: h[node][t] = sum_k x[node][k]*W[k][t]
// Also reduces es[node] = h·a_src, ed[node] = h·a_dst.
__global__ void k_linear(const float* __restrict__ x, const float* __restrict__ W,
                         const float* __restrict__ a_src, const float* __restrict__ a_dst,
                         float* __restrict__ h, float* __restrict__ es, float* __restrict__ ed,
                         int d_in) {
    int node = blockIdx.x;
    int t = threadIdx.x;
    __shared__ float xs[HID];
    __shared__ float s1[HID];
    __shared__ float s2[HID];
    if (t < d_in) xs[t] = x[(long long)node * d_in + t];
    __syncthreads();
    float acc = 0.f;
    for (int k = 0; k < d_in; ++k) acc += xs[k] * W[k * HID + t];
    h[(long long)node * HID + t] = acc;
    s1[t] = acc * a_src[t];
    s2[t] = acc * a_dst[t];
    __syncthreads();
    for (int off = 64; off > 0; off >>= 1) {
        if (t < off) { s1[t] += s1[t + off]; s2[t] += s2[t + off]; }
        __syncthreads();
    }
    if (t == 0) { es[node] = s1[0]; ed[node] = s2[0]; }
}

__global__ void k_init_md(unsigned* __restrict__ m, float* __restrict__ den, int n) {
    int i = blockIdx.x * blockDim.x + threadIdx.x;
    if (i < n) { m[i] = 0x007FFFFFu; /* enc(-inf) */ den[i] = 0.f; }
}

__global__ void k_edge_max(const int* __restrict__ ei, int E, int n,
                           const float* __restrict__ es, const float* __restrict__ ed,
                           unsigned* __restrict__ m_enc) {
    int i = blockIdx.x * blockDim.x + threadIdx.x;
    int M = E + n;
    if (i >= M) return;
    int s, d;
    if (i < E) { s = ei[i]; d = ei[E + i]; } else { s = d = i - E; }
    float e = es[s] + ed[d];
    e = e > 0.f ? e : NEG_SLOPE * e;
    atomicMax(&m_enc[d], fenc(e));
}

__global__ void k_edge_ex(const int* __restrict__ ei, int E, int n,
                          const float* __restrict__ es, const float* __restrict__ ed,
                          const unsigned* __restrict__ m_enc, float* __restrict__ den,
                          float* __restrict__ exb) {
    int i = blockIdx.x * blockDim.x + threadIdx.x;
    int M = E + n;
    if (i >= M) return;
    int s, d;
    if (i < E) { s = ei[i]; d = ei[E + i]; } else { s = d = i - E; }
    float e = es[s] + ed[d];
    e = e > 0.f ? e : NEG_SLOPE * e;
    float m = fdec(m_enc[d]);
    if (m < -3.0e38f) m = 0.f;  // where(isfinite(m), m, 0)
    float ex = expf(e - m);
    exb[i] = ex;
    atomicAdd(&den[d], ex);
}

// one thread per (edge, dim)
__global__ void k_edge_agg(const int* __restrict__ ei, int E, int n,
                           const float* __restrict__ exb, const float* __restrict__ den,
                           const float* __restrict__ h, float* __restrict__ agg) {
    long long gid = (long long)blockIdx.x * blockDim.x + threadIdx.x;
    int i = (int)(gid >> 7);
    if (i >= E + n) return;
    int dim = (int)(gid & 127);
    int s, d;
    if (i < E) { s = ei[i]; d = ei[E + i]; } else { s = d = i - E; }
    float alpha = exb[i] / fmaxf(den[d], 1e-16f);
    atomicAdd(&agg[(long long)d * HID + dim], alpha * h[(long long)s * HID + dim]);
}

__global__ void k_bias_relu(float* __restrict__ agg, const float* __restrict__ b, int total) {
    int i = blockIdx.x * blockDim.x + threadIdx.x;
    if (i < total) {
        float v = agg[i] + b[i & (HID - 1)];
        agg[i] = v > 0.f ? v : 0.f;
    }
}

__global__ void k_norm(const float* __restrict__ h, float* __restrict__ n2) {
    int node = blockIdx.x;
    int t = threadIdx.x;
    __shared__ float s[HID];
    float v = h[(long long)node * HID + t];
    s[t] = v * v;
    __syncthreads();
    for (int off = 64; off > 0; off >>= 1) {
        if (t < off) s[t] += s[t + off];
        __syncthreads();
    }
    if (t == 0) n2[node] = s[0];
}

// one block (256 threads) per collider node: top-3 nearest resting nodes, then
// atomically accumulate pooled_sum / cnt.
__global__ void k_knn(const float* __restrict__ hc, const float* __restrict__ hr,
                      const float* __restrict__ nr2, int n_r,
                      float* __restrict__ pooled, float* __restrict__ cnt) {
    int c = blockIdx.x;
    int t = threadIdx.x;
    __shared__ float xs[HID];
    __shared__ float red[256];
    __shared__ float ld2[256 * 3];
    __shared__ int lidx[256 * 3];
    __shared__ int bidx[3];
    if (t < HID) xs[t] = hc[(long long)c * HID + t];
    __syncthreads();
    float pn = (t < HID) ? xs[t] * xs[t] : 0.f;
    red[t] = pn;
    __syncthreads();
    for (int off = 128; off > 0; off >>= 1) {
        if (t < off) red[t] += red[t + off];
        __syncthreads();
    }
    float nc2 = red[0];

    float bd0 = INFINITY, bd1 = INFINITY, bd2 = INFINITY;
    int bi0 = 0x7fffffff, bi1 = 0x7fffffff, bi2 = 0x7fffffff;
    const float4* xs4 = (const float4*)xs;
    for (int j = t; j < n_r; j += 256) {
        const float4* r4 = (const float4*)(hr + (long long)j * HID);
        float dot = 0.f;
#pragma unroll
        for (int k = 0; k < HID / 4; ++k) {
            float4 a = xs4[k];
            float4 b = r4[k];
            dot += a.x * b.x + a.y * b.y + a.z * b.z + a.w * b.w;
        }
        float d2 = nc2 + nr2[j] - 2.f * dot;
        if (d2 < bd0 || (d2 == bd0 && j < bi0)) {
            bd2 = bd1; bi2 = bi1; bd1 = bd0; bi1 = bi0; bd0 = d2; bi0 = j;
        } else if (d2 < bd1 || (d2 == bd1 && j < bi1)) {
            bd2 = bd1; bi2 = bi1; bd1 = d2; bi1 = j;
        } else if (d2 < bd2 || (d2 == bd2 && j < bi2)) {
            bd2 = d2; bi2 = j;
        }
    }
    ld2[t * 3 + 0] = bd0; ld2[t * 3 + 1] = bd1; ld2[t * 3 + 2] = bd2;
    lidx[t * 3 + 0] = bi0; lidx[t * 3 + 1] = bi1; lidx[t * 3 + 2] = bi2;
    __syncthreads();
    if (t == 0) {
        float fd[3] = {INFINITY, INFINITY, INFINITY};
        int fi[3] = {0x7fffffff, 0x7fffffff, 0x7fffffff};
        for (int q = 0; q < 256 * 3; ++q) {
            float dv = ld2[q];
            int iv = lidx[q];
            if (dv < fd[0] || (dv == fd[0] && iv < fi[0])) {
                fd[2] = fd[1]; fi[2] = fi[1]; fd[1] = fd[0]; fi[1] = fi[0]; fd[0] = dv; fi[0] = iv;
            } else if (dv < fd[1] || (dv == fd[1] && iv < fi[1])) {
                fd[2] = fd[1]; fi[2] = fi[1]; fd[1] = dv; fi[1] = iv;
            } else if (dv < fd[2] || (dv == fd[2] && iv < fi[2])) {
                fd[2] = dv; fi[2] = iv;
            }
        }
        bidx[0] = fi[0]; bidx[1] = fi[1]; bidx[2] = fi[2];
    }
    __syncthreads();
    if (t < HID) {
        for (int j = 0; j < 3; ++j) atomicAdd(&pooled[(long long)bidx[j] * HID + t], xs[t]);
    }
    if (t == 0) {
        for (int j = 0; j < 3; ++j) atomicAdd(&cnt[bidx[j]], 1.0f);
    }
}

// one wave (64 lanes) per resting node: out[node][0..2]
__global__ void k_decode(const float* __restrict__ hr, const float* __restrict__ pooled,
                         const float* __restrict__ cnt, const float* __restrict__ Wd,
                         const float* __restrict__ bd, float* __restrict__ out, int n) {
    int node = blockIdx.x * (blockDim.x / 64) + (threadIdx.x >> 6);
    int lane = threadIdx.x & 63;
    if (node >= n) return;
    float c = fmaxf(cnt[node], 1.0f);
    float a0 = 0.f, a1 = 0.f, a2 = 0.f;
    for (int k = lane; k < HID; k += 64) {
        float v = hr[(long long)node * HID + k];
        a0 += v * Wd[k * 3 + 0];
        a1 += v * Wd[k * 3 + 1];
        a2 += v * Wd[k * 3 + 2];
        float p = pooled[(long long)node * HID + k] / c;
        a0 += p * Wd[(HID + k) * 3 + 0];
        a1 += p * Wd[(HID + k) * 3 + 1];
        a2 += p * Wd[(HID + k) * 3 + 2];
    }
    for (int off = 32; off > 0; off >>= 1) {
        a0 += __shfl_down(a0, off);
        a1 += __shfl_down(a1, off);
        a2 += __shfl_down(a2, off);
    }
    if (lane == 0) {
        out[(long long)node * 3 + 0] = a0 + bd[0];
        out[(long long)node * 3 + 1] = a1 + bd[1];
        out[(long long)node * 3 + 2] = a2 + bd[2];
    }
}

// ---------- launch ----------
static inline int cdiv(long long a, int b) { return (int)((a + b - 1) / b); }

extern "C" void kernel_launch(void* const* d_in, const int* in_sizes, int n_in,
                              void* d_out, int out_size, void* d_ws, size_t ws_size,
                              hipStream_t stream) {
    const float* x_r = (const float*)d_in[0];
    const float* x_c = (const float*)d_in[1];
    const int* ei_r = (const int*)d_in[2];
    const int* ei_c = (const int*)d_in[3];
    // d_in[4] = knn_k (always 3)
    const float* W_r1 = (const float*)d_in[5];
    const float* as_r1 = (const float*)d_in[6];
    const float* ad_r1 = (const float*)d_in[7];
    const float* b_r1 = (const float*)d_in[8];
    const float* W_r2 = (const float*)d_in[9];
    const float* as_r2 = (const float*)d_in[10];
    const float* ad_r2 = (const float*)d_in[11];
    const float* b_r2 = (const float*)d_in[12];
    const float* W_c1 = (const float*)d_in[13];
    const float* as_c1 = (const float*)d_in[14];
    const float* ad_c1 = (const float*)d_in[15];
    const float* b_c1 = (const float*)d_in[16];
    const float* W_c2 = (const float*)d_in[17];
    const float* as_c2 = (const float*)d_in[18];
    const float* ad_c2 = (const float*)d_in[19];
    const float* b_c2 = (const float*)d_in[20];
    const float* W_dec = (const float*)d_in[21];
    const float* b_dec = (const float*)d_in[22];
    float* out = (float*)d_out;

    const int N_R = in_sizes[0] / 6;
    const int N_C = in_sizes[1] / 6;
    const int E_R = in_sizes[2] / 2;
    const int E_C = in_sizes[3] / 2;

    float* ws = (float*)d_ws;
    size_t off = 0;
    auto alloc = [&](size_t nf) { float* p = ws + off; off += nf; return p; };
    float* r_h   = alloc((size_t)N_R * HID);
    float* r_agg = alloc((size_t)N_R * HID);
    float* c_h   = alloc((size_t)N_C * HID);
    float* c_agg = alloc((size_t)N_C * HID);
    float* pooled = alloc((size_t)N_R * HID);
    float* r_es = alloc(N_R);
    float* r_ed = alloc(N_R);
    float* r_den = alloc(N_R);
    unsigned* r_m = (unsigned*)alloc(N_R);
    float* c_es = alloc(N_C);
    float* c_ed = alloc(N_C);
    float* c_den = alloc(N_C);
    unsigned* c_m = (unsigned*)alloc(N_C);
    float* cnt = alloc(N_R);
    float* nr2 = alloc(N_R);
    int maxM = (E_R + N_R > E_C + N_C) ? (E_R + N_R) : (E_C + N_C);
    float* exb = alloc(maxM);
    (void)ws_size; (void)n_in; (void)out_size;

    auto gat = [&](const float* x, int d_in_dim, const int* ei, int E, int n,
                   const float* W, const float* as_, const float* ad_, const float* b,
                   float* h, float* agg, float* es, float* ed, unsigned* m, float* den) {
        k_linear<<<n, HID, 0, stream>>>(x, W, as_, ad_, h, es, ed, d_in_dim);
        k_init_md<<<cdiv(n, 256), 256, 0, stream>>>(m, den, n);
        hipMemsetAsync(agg, 0, (size_t)n * HID * sizeof(float), stream);
        int M = E + n;
        k_edge_max<<<cdiv(M, 256), 256, 0, stream>>>(ei, E, n, es, ed, m);
        k_edge_ex<<<cdiv(M, 256), 256, 0, stream>>>(ei, E, n, es, ed, m, den, exb);
        k_edge_agg<<<cdiv((long long)M * HID, 256), 256, 0, stream>>>(ei, E, n, exb, den, h, agg);
        k_bias_relu<<<cdiv((long long)n * HID, 256), 256, 0, stream>>>(agg, b, n * HID);
    };

    // resting branch: layer1 x_r -> r_agg, layer2 r_agg -> r_agg (h scratch r_h)
    gat(x_r, 6, ei_r, E_R, N_R, W_r1, as_r1, ad_r1, b_r1, r_h, r_agg, r_es, r_ed, r_m, r_den);
    gat(r_agg, HID, ei_r, E_R, N_R, W_r2, as_r2, ad_r2, b_r2, r_h, r_agg, r_es, r_ed, r_m, r_den);
    // collider branch
    gat(x_c, 6, ei_c, E_C, N_C, W_c1, as_c1, ad_c1, b_c1, c_h, c_agg, c_es, c_ed, c_m, c_den);
    gat(c_agg, HID, ei_c, E_C, N_C, W_c2, as_c2, ad_c2, b_c2, c_h, c_agg, c_es, c_ed, c_m, c_den);

    // KNN + pooled mean
    hipMemsetAsync(pooled, 0, (size_t)N_R * HID * sizeof(float), stream);
    hipMemsetAsync(cnt, 0, (size_t)N_R * sizeof(float), stream);
    k_norm<<<N_R, HID, 0, stream>>>(r_agg, nr2);
    k_knn<<<N_C, 256, 0, stream>>>(c_agg, r_agg, nr2, N_R, pooled, cnt);

    // decode
    k_decode<<<cdiv(N_R, 4), 256, 0, stream>>>(r_agg, pooled, cnt, W_dec, b_dec, out, N_R);
}

// Round 2
// 1700.121 us; speedup vs baseline: 5.0659x; 5.0659x over previous
//
#include <hip/hip_runtime.h>
#include <hip/hip_bf16.h>

#define HID 128
#define NEG_SLOPE 0.2f
#define KNN_TC 64
#define KNN_TR 64
#define NSPLIT 8

// ---------- helpers ----------
__device__ __forceinline__ unsigned fenc(float f) {
    unsigned u = __float_as_uint(f);
    return u ^ ((u >> 31) ? 0xFFFFFFFFu : 0x80000000u);
}
__device__ __forceinline__ float fdec(unsigned u) {
    unsigned v = (u & 0x80000000u) ? (u ^ 0x80000000u) : ~u;
    return __uint_as_float(v);
}
__device__ __forceinline__ bool cand_lt(float d1, int i1, float d2, int i2) {
    return d1 < d2 || (d1 == d2 && i1 < i2);
}

// ---------- GAT kernels (unchanged from round 1) ----------

__global__ void k_linear(const float* __restrict__ x, const float* __restrict__ W,
                         const float* __restrict__ a_src, const float* __restrict__ a_dst,
                         float* __restrict__ h, float* __restrict__ es, float* __restrict__ ed,
                         int d_in) {
    int node = blockIdx.x;
    int t = threadIdx.x;
    __shared__ float xs[HID];
    __shared__ float s1[HID];
    __shared__ float s2[HID];
    if (t < d_in) xs[t] = x[(long long)node * d_in + t];
    __syncthreads();
    float acc = 0.f;
    for (int k = 0; k < d_in; ++k) acc += xs[k] * W[k * HID + t];
    h[(long long)node * HID + t] = acc;
    s1[t] = acc * a_src[t];
    s2[t] = acc * a_dst[t];
    __syncthreads();
    for (int off = 64; off > 0; off >>= 1) {
        if (t < off) { s1[t] += s1[t + off]; s2[t] += s2[t + off]; }
        __syncthreads();
    }
    if (t == 0) { es[node] = s1[0]; ed[node] = s2[0]; }
}

__global__ void k_init_md(unsigned* __restrict__ m, float* __restrict__ den, int n) {
    int i = blockIdx.x * blockDim.x + threadIdx.x;
    if (i < n) { m[i] = 0x007FFFFFu; den[i] = 0.f; }
}

__global__ void k_edge_max(const int* __restrict__ ei, int E, int n,
                           const float* __restrict__ es, const float* __restrict__ ed,
                           unsigned* __restrict__ m_enc) {
    int i = blockIdx.x * blockDim.x + threadIdx.x;
    int M = E + n;
    if (i >= M) return;
    int s, d;
    if (i < E) { s = ei[i]; d = ei[E + i]; } else { s = d = i - E; }
    float e = es[s] + ed[d];
    e = e > 0.f ? e : NEG_SLOPE * e;
    atomicMax(&m_enc[d], fenc(e));
}

__global__ void k_edge_ex(const int* __restrict__ ei, int E, int n,
                          const float* __restrict__ es, const float* __restrict__ ed,
                          const unsigned* __restrict__ m_enc, float* __restrict__ den,
                          float* __restrict__ exb) {
    int i = blockIdx.x * blockDim.x + threadIdx.x;
    int M = E + n;
    if (i >= M) return;
    int s, d;
    if (i < E) { s = ei[i]; d = ei[E + i]; } else { s = d = i - E; }
    float e = es[s] + ed[d];
    e = e > 0.f ? e : NEG_SLOPE * e;
    float m = fdec(m_enc[d]);
    if (m < -3.0e38f) m = 0.f;
    float ex = expf(e - m);
    exb[i] = ex;
    atomicAdd(&den[d], ex);
}

__global__ void k_edge_agg(const int* __restrict__ ei, int E, int n,
                           const float* __restrict__ exb, const float* __restrict__ den,
                           const float* __restrict__ h, float* __restrict__ agg) {
    long long gid = (long long)blockIdx.x * blockDim.x + threadIdx.x;
    int i = (int)(gid >> 7);
    if (i >= E + n) return;
    int dim = (int)(gid & 127);
    int s, d;
    if (i < E) { s = ei[i]; d = ei[E + i]; } else { s = d = i - E; }
    float alpha = exb[i] / fmaxf(den[d], 1e-16f);
    atomicAdd(&agg[(long long)d * HID + dim], alpha * h[(long long)s * HID + dim]);
}

__global__ void k_bias_relu(float* __restrict__ agg, const float* __restrict__ b, int total) {
    int i = blockIdx.x * blockDim.x + threadIdx.x;
    if (i < total) {
        float v = agg[i] + b[i & (HID - 1)];
        agg[i] = v > 0.f ? v : 0.f;
    }
}

__global__ void k_norm(const float* __restrict__ h, float* __restrict__ n2) {
    int node = blockIdx.x;
    int t = threadIdx.x;
    __shared__ float s[HID];
    float v = h[(long long)node * HID + t];
    s[t] = v * v;
    __syncthreads();
    for (int off = 64; off > 0; off >>= 1) {
        if (t < off) s[t] += s[t + off];
        __syncthreads();
    }
    if (t == 0) n2[node] = s[0];
}

// ---------- tiled KNN ----------
// Grid: (ceil(N_C/64), NSPLIT), 256 threads. Each block: 64 colliders x one
// resting chunk, LDS-tiled 64x64, 4x4 register micro-tile per thread.
// Emits per-(collider, split) top-3 candidates (score = |r|^2 - 2 c.r).
__global__ __launch_bounds__(256) void k_knn2(
    const float* __restrict__ hc, const float* __restrict__ hr,
    const float* __restrict__ nr2, int n_c, int n_r, int rs_chunk,
    float* __restrict__ cand_d, int* __restrict__ cand_i) {
    __shared__ float4 smem[4096];      // 64 KB: sc=[0,2048), sr=[2048,4096)
    float4* sc = smem;
    float4* sr = smem + 2048;
    int t = threadIdx.x;
    int c0 = blockIdx.x * KNN_TC;
    int rs = blockIdx.y;
    int rbeg = rs * rs_chunk;
    int rend = min(rbeg + rs_chunk, n_r);

    // stage collider tile (float4-unit XOR swizzle: k4 ^ (row&7))
#pragma unroll
    for (int s = 0; s < 8; ++s) {
        int f = t + 256 * s;
        int row = f >> 5, k4 = f & 31;
        int c = c0 + row;
        float4 v = make_float4(0.f, 0.f, 0.f, 0.f);
        if (c < n_c) v = ((const float4*)hc)[c * 32 + k4];
        sc[row * 32 + (k4 ^ (row & 7))] = v;
    }

    int tcg = t >> 4, trg = t & 15;
    int swc = tcg & 7, swr = trg & 7;

    float bd[4][3]; int bi[4][3];
#pragma unroll
    for (int i = 0; i < 4; ++i)
#pragma unroll
        for (int q = 0; q < 3; ++q) { bd[i][q] = INFINITY; bi[i][q] = 0x7fffffff; }

    for (int rt = rbeg; rt < rend; rt += KNN_TR) {
        __syncthreads();
#pragma unroll
        for (int s = 0; s < 8; ++s) {
            int f = t + 256 * s;
            int row = f >> 5, k4 = f & 31;
            int r = rt + row;
            float4 v = make_float4(0.f, 0.f, 0.f, 0.f);
            if (r < rend) v = ((const float4*)hr)[r * 32 + k4];
            sr[row * 32 + (k4 ^ (row & 7))] = v;
        }
        __syncthreads();

        float acc[4][4] = {{0.f}};
#pragma unroll 4
        for (int k4 = 0; k4 < 32; ++k4) {
            float4 cf[4], rf[4];
#pragma unroll
            for (int i = 0; i < 4; ++i) cf[i] = sc[(tcg + 16 * i) * 32 + (k4 ^ swc)];
#pragma unroll
            for (int j = 0; j < 4; ++j) rf[j] = sr[(trg + 16 * j) * 32 + (k4 ^ swr)];
#pragma unroll
            for (int i = 0; i < 4; ++i)
#pragma unroll
                for (int j = 0; j < 4; ++j)
                    acc[i][j] += cf[i].x * rf[j].x + cf[i].y * rf[j].y
                               + cf[i].z * rf[j].z + cf[i].w * rf[j].w;
        }
        // per-thread running top-3 update
#pragma unroll
        for (int j = 0; j < 4; ++j) {
            int r = rt + trg + 16 * j;
            if (r >= rend) continue;
            float nrr = nr2[r];
#pragma unroll
            for (int i = 0; i < 4; ++i) {
                float s = nrr - 2.f * acc[i][j];
                if (cand_lt(s, r, bd[i][0], bi[i][0])) {
                    bd[i][2]=bd[i][1]; bi[i][2]=bi[i][1];
                    bd[i][1]=bd[i][0]; bi[i][1]=bi[i][0];
                    bd[i][0]=s; bi[i][0]=r;
                } else if (cand_lt(s, r, bd[i][1], bi[i][1])) {
                    bd[i][2]=bd[i][1]; bi[i][2]=bi[i][1];
                    bd[i][1]=s; bi[i][1]=r;
                } else if (cand_lt(s, r, bd[i][2], bi[i][2])) {
                    bd[i][2]=s; bi[i][2]=r;
                }
            }
        }
    }
    __syncthreads();
    // dump per-thread top3 to LDS (aliases sc), merge 16 threads per collider
    float* md = (float*)smem;                  // 3072 floats
    int* mi = (int*)(((float*)smem) + 3072);   // 3072 ints
#pragma unroll
    for (int i = 0; i < 4; ++i) {
        int slot = i * 16 + tcg;               // = local collider index
        int base = (slot * 16 + trg) * 3;
#pragma unroll
        for (int q = 0; q < 3; ++q) { md[base + q] = bd[i][q]; mi[base + q] = bi[i][q]; }
    }
    __syncthreads();
    if (t < KNN_TC) {
        float fd[3] = {INFINITY, INFINITY, INFINITY};
        int fi[3] = {0x7fffffff, 0x7fffffff, 0x7fffffff};
        for (int g = 0; g < 16; ++g) {
            int base = (t * 16 + g) * 3;
            for (int q = 0; q < 3; ++q) {
                float dv = md[base + q]; int iv = mi[base + q];
                if (cand_lt(dv, iv, fd[0], fi[0])) {
                    fd[2]=fd[1]; fi[2]=fi[1]; fd[1]=fd[0]; fi[1]=fi[0]; fd[0]=dv; fi[0]=iv;
                } else if (cand_lt(dv, iv, fd[1], fi[1])) {
                    fd[2]=fd[1]; fi[2]=fi[1]; fd[1]=dv; fi[1]=iv;
                } else if (cand_lt(dv, iv, fd[2], fi[2])) {
                    fd[2]=dv; fi[2]=iv;
                }
            }
        }
        int cg = c0 + t;
        if (cg < n_c) {
            int ob = (cg * NSPLIT + rs) * 3;
            for (int q = 0; q < 3; ++q) { cand_d[ob + q] = fd[q]; cand_i[ob + q] = fi[q]; }
        }
    }
}

// one block (128 threads) per collider: merge NSPLIT*3 candidates, accumulate.
__global__ void k_knn_merge(const float* __restrict__ cand_d, const int* __restrict__ cand_i,
                            const float* __restrict__ hc, int n_r,
                            float* __restrict__ pooled, float* __restrict__ cnt) {
    int c = blockIdx.x;
    int t = threadIdx.x;
    __shared__ int bidx[3];
    if (t == 0) {
        float fd[3] = {INFINITY, INFINITY, INFINITY};
        int fi[3] = {0x7fffffff, 0x7fffffff, 0x7fffffff};
        for (int q = 0; q < NSPLIT * 3; ++q) {
            float dv = cand_d[c * NSPLIT * 3 + q];
            int iv = cand_i[c * NSPLIT * 3 + q];
            if (cand_lt(dv, iv, fd[0], fi[0])) {
                fd[2]=fd[1]; fi[2]=fi[1]; fd[1]=fd[0]; fi[1]=fi[0]; fd[0]=dv; fi[0]=iv;
            } else if (cand_lt(dv, iv, fd[1], fi[1])) {
                fd[2]=fd[1]; fi[2]=fi[1]; fd[1]=dv; fi[1]=iv;
            } else if (cand_lt(dv, iv, fd[2], fi[2])) {
                fd[2]=dv; fi[2]=iv;
            }
        }
        bidx[0] = fi[0]; bidx[1] = fi[1]; bidx[2] = fi[2];
    }
    __syncthreads();
    float v = hc[(long long)c * HID + t];
    for (int q = 0; q < 3; ++q) {
        int b = bidx[q];
        if (b >= 0 && b < n_r) {
            atomicAdd(&pooled[(long long)b * HID + t], v);
            if (t == 0) atomicAdd(&cnt[b], 1.0f);
        }
    }
}

// one wave (64 lanes) per resting node
__global__ void k_decode(const float* __restrict__ hr, const float* __restrict__ pooled,
                         const float* __restrict__ cnt, const float* __restrict__ Wd,
                         const float* __restrict__ bd, float* __restrict__ out, int n) {
    int node = blockIdx.x * (blockDim.x / 64) + (threadIdx.x >> 6);
    int lane = threadIdx.x & 63;
    if (node >= n) return;
    float c = fmaxf(cnt[node], 1.0f);
    float a0 = 0.f, a1 = 0.f, a2 = 0.f;
    for (int k = lane; k < HID; k += 64) {
        float v = hr[(long long)node * HID + k];
        a0 += v * Wd[k * 3 + 0];
        a1 += v * Wd[k * 3 + 1];
        a2 += v * Wd[k * 3 + 2];
        float p = pooled[(long long)node * HID + k] / c;
        a0 += p * Wd[(HID + k) * 3 + 0];
        a1 += p * Wd[(HID + k) * 3 + 1];
        a2 += p * Wd[(HID + k) * 3 + 2];
    }
    for (int off = 32; off > 0; off >>= 1) {
        a0 += __shfl_down(a0, off);
        a1 += __shfl_down(a1, off);
        a2 += __shfl_down(a2, off);
    }
    if (lane == 0) {
        out[(long long)node * 3 + 0] = a0 + bd[0];
        out[(long long)node * 3 + 1] = a1 + bd[1];
        out[(long long)node * 3 + 2] = a2 + bd[2];
    }
}

// ---------- launch ----------
static inline int cdiv(long long a, int b) { return (int)((a + b - 1) / b); }

extern "C" void kernel_launch(void* const* d_in, const int* in_sizes, int n_in,
                              void* d_out, int out_size, void* d_ws, size_t ws_size,
                              hipStream_t stream) {
    const float* x_r = (const float*)d_in[0];
    const float* x_c = (const float*)d_in[1];
    const int* ei_r = (const int*)d_in[2];
    const int* ei_c = (const int*)d_in[3];
    const float* W_r1 = (const float*)d_in[5];
    const float* as_r1 = (const float*)d_in[6];
    const float* ad_r1 = (const float*)d_in[7];
    const float* b_r1 = (const float*)d_in[8];
    const float* W_r2 = (const float*)d_in[9];
    const float* as_r2 = (const float*)d_in[10];
    const float* ad_r2 = (const float*)d_in[11];
    const float* b_r2 = (const float*)d_in[12];
    const float* W_c1 = (const float*)d_in[13];
    const float* as_c1 = (const float*)d_in[14];
    const float* ad_c1 = (const float*)d_in[15];
    const float* b_c1 = (const float*)d_in[16];
    const float* W_c2 = (const float*)d_in[17];
    const float* as_c2 = (const float*)d_in[18];
    const float* ad_c2 = (const float*)d_in[19];
    const float* b_c2 = (const float*)d_in[20];
    const float* W_dec = (const float*)d_in[21];
    const float* b_dec = (const float*)d_in[22];
    float* out = (float*)d_out;

    const int N_R = in_sizes[0] / 6;
    const int N_C = in_sizes[1] / 6;
    const int E_R = in_sizes[2] / 2;
    const int E_C = in_sizes[3] / 2;

    float* ws = (float*)d_ws;
    size_t off = 0;
    auto alloc = [&](size_t nf) { float* p = ws + off; off += nf; return p; };
    float* r_h   = alloc((size_t)N_R * HID);
    float* r_agg = alloc((size_t)N_R * HID);
    float* c_h   = alloc((size_t)N_C * HID);
    float* c_agg = alloc((size_t)N_C * HID);
    float* pooled = alloc((size_t)N_R * HID);
    float* r_es = alloc(N_R);
    float* r_ed = alloc(N_R);
    float* r_den = alloc(N_R);
    unsigned* r_m = (unsigned*)alloc(N_R);
    float* c_es = alloc(N_C);
    float* c_ed = alloc(N_C);
    float* c_den = alloc(N_C);
    unsigned* c_m = (unsigned*)alloc(N_C);
    float* cnt = alloc(N_R);
    float* nr2 = alloc(N_R);
    float* cand_d = alloc((size_t)N_C * NSPLIT * 3);
    int* cand_i = (int*)alloc((size_t)N_C * NSPLIT * 3);
    int maxM = (E_R + N_R > E_C + N_C) ? (E_R + N_R) : (E_C + N_C);
    float* exb = alloc(maxM);
    (void)ws_size; (void)n_in; (void)out_size;

    auto gat = [&](const float* x, int d_in_dim, const int* ei, int E, int n,
                   const float* W, const float* as_, const float* ad_, const float* b,
                   float* h, float* agg, float* es, float* ed, unsigned* m, float* den) {
        k_linear<<<n, HID, 0, stream>>>(x, W, as_, ad_, h, es, ed, d_in_dim);
        k_init_md<<<cdiv(n, 256), 256, 0, stream>>>(m, den, n);
        hipMemsetAsync(agg, 0, (size_t)n * HID * sizeof(float), stream);
        int M = E + n;
        k_edge_max<<<cdiv(M, 256), 256, 0, stream>>>(ei, E, n, es, ed, m);
        k_edge_ex<<<cdiv(M, 256), 256, 0, stream>>>(ei, E, n, es, ed, m, den, exb);
        k_edge_agg<<<cdiv((long long)M * HID, 256), 256, 0, stream>>>(ei, E, n, exb, den, h, agg);
        k_bias_relu<<<cdiv((long long)n * HID, 256), 256, 0, stream>>>(agg, b, n * HID);
    };

    gat(x_r, 6, ei_r, E_R, N_R, W_r1, as_r1, ad_r1, b_r1, r_h, r_agg, r_es, r_ed, r_m, r_den);
    gat(r_agg, HID, ei_r, E_R, N_R, W_r2, as_r2, ad_r2, b_r2, r_h, r_agg, r_es, r_ed, r_m, r_den);
    gat(x_c, 6, ei_c, E_C, N_C, W_c1, as_c1, ad_c1, b_c1, c_h, c_agg, c_es, c_ed, c_m, c_den);
    gat(c_agg, HID, ei_c, E_C, N_C, W_c2, as_c2, ad_c2, b_c2, c_h, c_agg, c_es, c_ed, c_m, c_den);

    // KNN + pooled mean
    hipMemsetAsync(pooled, 0, (size_t)N_R * HID * sizeof(float), stream);
    hipMemsetAsync(cnt, 0, (size_t)N_R * sizeof(float), stream);
    k_norm<<<N_R, HID, 0, stream>>>(r_agg, nr2);
    int RS = cdiv(N_R, NSPLIT);
    dim3 kgrid(cdiv(N_C, KNN_TC), NSPLIT);
    k_knn2<<<kgrid, 256, 0, stream>>>(c_agg, r_agg, nr2, N_C, N_R, RS, cand_d, cand_i);
    k_knn_merge<<<N_C, HID, 0, stream>>>(cand_d, cand_i, c_agg, N_R, pooled, cnt);

    // decode
    k_decode<<<cdiv(N_R, 4), 256, 0, stream>>>(r_agg, pooled, cnt, W_dec, b_dec, out, N_R);
}

// Round 4
// 1061.086 us; speedup vs baseline: 8.1169x; 1.6022x over previous
//
#include <hip/hip_runtime.h>
#include <hip/hip_bf16.h>

#define HID 128
#define NEG_SLOPE 0.2f
#define CSPLIT 6

typedef _Float16 f16x8 __attribute__((ext_vector_type(8)));
typedef float f32x4 __attribute__((ext_vector_type(4)));

// ---------- helpers ----------
__device__ __forceinline__ unsigned fenc(float f) {
    unsigned u = __float_as_uint(f);
    return u ^ ((u >> 31) ? 0xFFFFFFFFu : 0x80000000u);
}
__device__ __forceinline__ float fdec(unsigned u) {
    unsigned v = (u & 0x80000000u) ? (u ^ 0x80000000u) : ~u;
    return __uint_as_float(v);
}
__device__ __forceinline__ bool cand_lt(float d1, int i1, float d2, int i2) {
    return d1 < d2 || (d1 == d2 && i1 < i2);
}
__device__ __forceinline__ void ins4(float s, int r, float bd[4], int bi[4]) {
    if (!cand_lt(s, r, bd[3], bi[3])) return;
    if (cand_lt(s, r, bd[0], bi[0])) {
        bd[3]=bd[2];bi[3]=bi[2]; bd[2]=bd[1];bi[2]=bi[1]; bd[1]=bd[0];bi[1]=bi[0]; bd[0]=s;bi[0]=r;
    } else if (cand_lt(s, r, bd[1], bi[1])) {
        bd[3]=bd[2];bi[3]=bi[2]; bd[2]=bd[1];bi[2]=bi[1]; bd[1]=s;bi[1]=r;
    } else if (cand_lt(s, r, bd[2], bi[2])) {
        bd[3]=bd[2];bi[3]=bi[2]; bd[2]=s;bi[2]=r;
    } else {
        bd[3]=s;bi[3]=r;
    }
}
__device__ __forceinline__ void ins3(float s, int r, float fd[3], int fi[3]) {
    if (!cand_lt(s, r, fd[2], fi[2])) return;
    if (cand_lt(s, r, fd[0], fi[0])) {
        fd[2]=fd[1];fi[2]=fi[1]; fd[1]=fd[0];fi[1]=fi[0]; fd[0]=s;fi[0]=r;
    } else if (cand_lt(s, r, fd[1], fi[1])) {
        fd[2]=fd[1];fi[2]=fi[1]; fd[1]=s;fi[1]=r;
    } else {
        fd[2]=s;fi[2]=r;
    }
}

// ---------- GAT kernels (unchanged) ----------

__global__ void k_linear(const float* __restrict__ x, const float* __restrict__ W,
                         const float* __restrict__ a_src, const float* __restrict__ a_dst,
                         float* __restrict__ h, float* __restrict__ es, float* __restrict__ ed,
                         int d_in) {
    int node = blockIdx.x;
    int t = threadIdx.x;
    __shared__ float xs[HID];
    __shared__ float s1[HID];
    __shared__ float s2[HID];
    if (t < d_in) xs[t] = x[(long long)node * d_in + t];
    __syncthreads();
    float acc = 0.f;
    for (int k = 0; k < d_in; ++k) acc += xs[k] * W[k * HID + t];
    h[(long long)node * HID + t] = acc;
    s1[t] = acc * a_src[t];
    s2[t] = acc * a_dst[t];
    __syncthreads();
    for (int off = 64; off > 0; off >>= 1) {
        if (t < off) { s1[t] += s1[t + off]; s2[t] += s2[t + off]; }
        __syncthreads();
    }
    if (t == 0) { es[node] = s1[0]; ed[node] = s2[0]; }
}

__global__ void k_init_md(unsigned* __restrict__ m, float* __restrict__ den, int n) {
    int i = blockIdx.x * blockDim.x + threadIdx.x;
    if (i < n) { m[i] = 0x007FFFFFu; den[i] = 0.f; }
}

__global__ void k_edge_max(const int* __restrict__ ei, int E, int n,
                           const float* __restrict__ es, const float* __restrict__ ed,
                           unsigned* __restrict__ m_enc) {
    int i = blockIdx.x * blockDim.x + threadIdx.x;
    int M = E + n;
    if (i >= M) return;
    int s, d;
    if (i < E) { s = ei[i]; d = ei[E + i]; } else { s = d = i - E; }
    float e = es[s] + ed[d];
    e = e > 0.f ? e : NEG_SLOPE * e;
    atomicMax(&m_enc[d], fenc(e));
}

__global__ void k_edge_ex(const int* __restrict__ ei, int E, int n,
                          const float* __restrict__ es, const float* __restrict__ ed,
                          const unsigned* __restrict__ m_enc, float* __restrict__ den,
                          float* __restrict__ exb) {
    int i = blockIdx.x * blockDim.x + threadIdx.x;
    int M = E + n;
    if (i >= M) return;
    int s, d;
    if (i < E) { s = ei[i]; d = ei[E + i]; } else { s = d = i - E; }
    float e = es[s] + ed[d];
    e = e > 0.f ? e : NEG_SLOPE * e;
    float m = fdec(m_enc[d]);
    if (m < -3.0e38f) m = 0.f;
    float ex = expf(e - m);
    exb[i] = ex;
    atomicAdd(&den[d], ex);
}

__global__ void k_edge_agg(const int* __restrict__ ei, int E, int n,
                           const float* __restrict__ exb, const float* __restrict__ den,
                           const float* __restrict__ h, float* __restrict__ agg) {
    long long gid = (long long)blockIdx.x * blockDim.x + threadIdx.x;
    int i = (int)(gid >> 7);
    if (i >= E + n) return;
    int dim = (int)(gid & 127);
    int s, d;
    if (i < E) { s = ei[i]; d = ei[E + i]; } else { s = d = i - E; }
    float alpha = exb[i] / fmaxf(den[d], 1e-16f);
    atomicAdd(&agg[(long long)d * HID + dim], alpha * h[(long long)s * HID + dim]);
}

__global__ void k_bias_relu(float* __restrict__ agg, const float* __restrict__ b, int total) {
    int i = blockIdx.x * blockDim.x + threadIdx.x;
    if (i < total) {
        float v = agg[i] + b[i & (HID - 1)];
        agg[i] = v > 0.f ? v : 0.f;
    }
}

// norm (optional) + fp32 -> f16 split
__global__ void k_norm_split(const float* __restrict__ h, float* __restrict__ n2,
                             _Float16* __restrict__ h2, int do_norm) {
    int node = blockIdx.x;
    int t = threadIdx.x;
    float v = h[(long long)node * HID + t];
    h2[(long long)node * HID + t] = (_Float16)v;
    if (do_norm) {
        __shared__ float s[HID];
        s[t] = v * v;
        __syncthreads();
        for (int off = 64; off > 0; off >>= 1) {
            if (t < off) s[t] += s[t + off];
            __syncthreads();
        }
        if (t == 0) n2[node] = s[0];
    }
}

// ---------- MFMA KNN scan ----------
// grid (ceil(N_C/128), CSPLIT), 256 thr = 4 waves. Each wave: 2 col-blocks of
// 16 colliders (B-frags in regs, full K=128). Resting streamed through
// XOR-swizzled LDS in 64-row double-buffered chunks. Per-lane top-4 candidate
// indices per (colblock, row-class) written to cand_i.
__global__ __launch_bounds__(256) void k_knn_scan(
    const _Float16* __restrict__ hr2, const _Float16* __restrict__ hc2,
    const float* __restrict__ nr2, int n_c, int n_r, int rs_chunk,
    int* __restrict__ cand_i) {
    __shared__ _Float16 lds[2][64 * 128];
    int t = threadIdx.x, w = t >> 6, lane = t & 63;
    int li = lane & 15, q = lane >> 4;
    int c0 = blockIdx.x * 128;
    int split = blockIdx.y;
    int rbeg = split * rs_chunk;
    int rows = min(rs_chunk, n_r - rbeg);
    int rend = rbeg + rows;

    // collider fragments (B): lane holds col=li, k = ks*32 + q*8 .. +7
    f16x8 bf[2][4];
#pragma unroll
    for (int cb = 0; cb < 2; ++cb) {
        int c = c0 + w * 32 + cb * 16 + li;
        int cc = min(c, n_c - 1);
#pragma unroll
        for (int ks = 0; ks < 4; ++ks)
            bf[cb][ks] = *(const f16x8*)(hc2 + (size_t)cc * HID + ks * 32 + q * 8);
    }

    float bd[2][4]; int bi[2][4];
#pragma unroll
    for (int cb = 0; cb < 2; ++cb)
#pragma unroll
        for (int k = 0; k < 4; ++k) { bd[cb][k] = INFINITY; bi[cb][k] = 0x7fffffff; }

    int nch = (rows + 63) >> 6;

    // stage chunk 0 into buf 0 (reg-staged, swizzled ds_write)
    {
        int R = rbeg;
#pragma unroll
        for (int gi = 0; gi < 4; ++gi) {
            int lr = (w * 4 + gi) * 4 + q;
            int gr = min(R + lr, n_r - 1);
            f16x8 v = *(const f16x8*)(hr2 + (size_t)gr * HID + li * 8);
            *(f16x8*)(&lds[0][lr * HID + ((li ^ (lr & 7)) << 3)]) = v;
        }
    }
    __syncthreads();

    for (int ch = 0; ch < nch; ++ch) {
        int cur = ch & 1;
        // prefetch next chunk into other buffer
        if (ch + 1 < nch) {
            int R = rbeg + (ch + 1) * 64;
#pragma unroll
            for (int gi = 0; gi < 4; ++gi) {
                int lr = (w * 4 + gi) * 4 + q;
                int gr = min(R + lr, n_r - 1);
                f16x8 v = *(const f16x8*)(hr2 + (size_t)gr * HID + li * 8);
                *(f16x8*)(&lds[cur ^ 1][lr * HID + ((li ^ (lr & 7)) << 3)]) = v;
            }
        }
        int R = rbeg + ch * 64;
        int rows_rem = rend - R;
        const _Float16* buf = lds[cur];
#pragma unroll
        for (int tt = 0; tt < 4; ++tt) {
            int br = tt * 16;
            if (br < rows_rem) {
                f32x4 a0 = {0.f, 0.f, 0.f, 0.f};
                f32x4 a1 = {0.f, 0.f, 0.f, 0.f};
                int lr = br + li;
                int sw = lr & 7;
#pragma unroll
                for (int ks = 0; ks < 4; ++ks) {
                    f16x8 af = *(const f16x8*)(&buf[lr * HID + (((ks * 4 + q) ^ sw) << 3)]);
                    a0 = __builtin_amdgcn_mfma_f32_16x16x32_f16(af, bf[0][ks], a0, 0, 0, 0);
                    a1 = __builtin_amdgcn_mfma_f32_16x16x32_f16(af, bf[1][ks], a1, 0, 0, 0);
                }
                int r_base = R + br + q * 4;
                float4 nrv = *(const float4*)(nr2 + r_base);
                float sv[4] = {nrv.x, nrv.y, nrv.z, nrv.w};
#pragma unroll
                for (int i = 0; i < 4; ++i) {
                    int r = r_base + i;
                    if (r < rend) {
                        float s0 = sv[i] - 2.f * a0[i];
                        ins4(s0, r, bd[0], bi[0]);
                        float s1 = sv[i] - 2.f * a1[i];
                        ins4(s1, r, bd[1], bi[1]);
                    }
                }
            }
        }
        __syncthreads();
    }

    // write candidate indices
#pragma unroll
    for (int cb = 0; cb < 2; ++cb) {
        int c = c0 + w * 32 + cb * 16 + li;
        if (c < n_c) {
            size_t base = ((size_t)(c * CSPLIT + split) * 4 + q) * 4;
#pragma unroll
            for (int k = 0; k < 4; ++k) cand_i[base + k] = bi[cb][k];
        }
    }
}

// ---------- exact rerank + pooling ----------
// one block (128 thr, 2 waves) per collider: exact fp32 distance for the 96
// candidates, top-3 with (d, idx) tie-break, then pooled/cnt accumulation.
__global__ __launch_bounds__(128) void k_rerank(
    const int* __restrict__ cand_i, const float* __restrict__ hc,
    const float* __restrict__ hr, const float* __restrict__ nr2,
    int n_r, float* __restrict__ pooled, float* __restrict__ cnt) {
    int c = blockIdx.x;
    int t = threadIdx.x, w = t >> 6, lane = t & 63;
    __shared__ float wd[2][3];
    __shared__ int wi[2][3];
    __shared__ int bidx[3];
    float hc0 = hc[(size_t)c * HID + lane];
    float hc1 = hc[(size_t)c * HID + 64 + lane];
    float fd[3] = {INFINITY, INFINITY, INFINITY};
    int fi[3] = {0x7fffffff, 0x7fffffff, 0x7fffffff};
    for (int jj = 0; jj < CSPLIT * 16 / 2; ++jj) {
        int j = w * (CSPLIT * 16 / 2) + jj;
        int r = cand_i[(size_t)c * (CSPLIT * 16) + j];
        if (r < 0 || r >= n_r) continue;
        float p = hc0 * hr[(size_t)r * HID + lane] + hc1 * hr[(size_t)r * HID + 64 + lane];
#pragma unroll
        for (int o = 1; o < 64; o <<= 1) p += __shfl_xor(p, o);
        float s = nr2[r] - 2.f * p;
        ins3(s, r, fd, fi);
    }
    if (lane == 0) {
#pragma unroll
        for (int k = 0; k < 3; ++k) { wd[w][k] = fd[k]; wi[w][k] = fi[k]; }
    }
    __syncthreads();
    if (t == 0) {
        float gd[3] = {INFINITY, INFINITY, INFINITY};
        int gi[3] = {0x7fffffff, 0x7fffffff, 0x7fffffff};
        for (int ww = 0; ww < 2; ++ww)
            for (int k = 0; k < 3; ++k) ins3(wd[ww][k], wi[ww][k], gd, gi);
        bidx[0] = gi[0]; bidx[1] = gi[1]; bidx[2] = gi[2];
    }
    __syncthreads();
    float v = hc[(size_t)c * HID + t];
#pragma unroll
    for (int k = 0; k < 3; ++k) {
        int b = bidx[k];
        if (b >= 0 && b < n_r) {
            atomicAdd(&pooled[(size_t)b * HID + t], v);
            if (t == 0) atomicAdd(&cnt[b], 1.0f);
        }
    }
}

// one wave (64 lanes) per resting node
__global__ void k_decode(const float* __restrict__ hr, const float* __restrict__ pooled,
                         const float* __restrict__ cnt, const float* __restrict__ Wd,
                         const float* __restrict__ bd, float* __restrict__ out, int n) {
    int node = blockIdx.x * (blockDim.x / 64) + (threadIdx.x >> 6);
    int lane = threadIdx.x & 63;
    if (node >= n) return;
    float c = fmaxf(cnt[node], 1.0f);
    float a0 = 0.f, a1 = 0.f, a2 = 0.f;
    for (int k = lane; k < HID; k += 64) {
        float v = hr[(long long)node * HID + k];
        a0 += v * Wd[k * 3 + 0];
        a1 += v * Wd[k * 3 + 1];
        a2 += v * Wd[k * 3 + 2];
        float p = pooled[(long long)node * HID + k] / c;
        a0 += p * Wd[(HID + k) * 3 + 0];
        a1 += p * Wd[(HID + k) * 3 + 1];
        a2 += p * Wd[(HID + k) * 3 + 2];
    }
    for (int off = 32; off > 0; off >>= 1) {
        a0 += __shfl_down(a0, off);
        a1 += __shfl_down(a1, off);
        a2 += __shfl_down(a2, off);
    }
    if (lane == 0) {
        out[(long long)node * 3 + 0] = a0 + bd[0];
        out[(long long)node * 3 + 1] = a1 + bd[1];
        out[(long long)node * 3 + 2] = a2 + bd[2];
    }
}

// ---------- launch ----------
static inline int cdiv(long long a, int b) { return (int)((a + b - 1) / b); }

extern "C" void kernel_launch(void* const* d_in, const int* in_sizes, int n_in,
                              void* d_out, int out_size, void* d_ws, size_t ws_size,
                              hipStream_t stream) {
    const float* x_r = (const float*)d_in[0];
    const float* x_c = (const float*)d_in[1];
    const int* ei_r = (const int*)d_in[2];
    const int* ei_c = (const int*)d_in[3];
    const float* W_r1 = (const float*)d_in[5];
    const float* as_r1 = (const float*)d_in[6];
    const float* ad_r1 = (const float*)d_in[7];
    const float* b_r1 = (const float*)d_in[8];
    const float* W_r2 = (const float*)d_in[9];
    const float* as_r2 = (const float*)d_in[10];
    const float* ad_r2 = (const float*)d_in[11];
    const float* b_r2 = (const float*)d_in[12];
    const float* W_c1 = (const float*)d_in[13];
    const float* as_c1 = (const float*)d_in[14];
    const float* ad_c1 = (const float*)d_in[15];
    const float* b_c1 = (const float*)d_in[16];
    const float* W_c2 = (const float*)d_in[17];
    const float* as_c2 = (const float*)d_in[18];
    const float* ad_c2 = (const float*)d_in[19];
    const float* b_c2 = (const float*)d_in[20];
    const float* W_dec = (const float*)d_in[21];
    const float* b_dec = (const float*)d_in[22];
    float* out = (float*)d_out;

    const int N_R = in_sizes[0] / 6;
    const int N_C = in_sizes[1] / 6;
    const int E_R = in_sizes[2] / 2;
    const int E_C = in_sizes[3] / 2;

    float* ws = (float*)d_ws;
    size_t off = 0;
    auto alloc = [&](size_t nf) {
        float* p = ws + off;
        off += (nf + 3) & ~(size_t)3;
        return p;
    };
    float* r_h    = alloc((size_t)N_R * HID);
    float* r_agg  = alloc((size_t)N_R * HID);
    float* c_h    = alloc((size_t)N_C * HID);
    float* c_agg  = alloc((size_t)N_C * HID);
    float* pooled = alloc((size_t)N_R * HID);
    float* r_es = alloc(N_R);
    float* r_ed = alloc(N_R);
    float* r_den = alloc(N_R);
    unsigned* r_m = (unsigned*)alloc(N_R);
    float* c_es = alloc(N_C);
    float* c_ed = alloc(N_C);
    float* c_den = alloc(N_C);
    unsigned* c_m = (unsigned*)alloc(N_C);
    float* cnt = alloc(N_R);
    float* nr2 = alloc((size_t)N_R + 64);
    _Float16* hr2 = (_Float16*)alloc((size_t)N_R * HID / 2);
    _Float16* hc2 = (_Float16*)alloc((size_t)N_C * HID / 2);
    int* cand_i = (int*)alloc((size_t)N_C * CSPLIT * 16);
    int maxM = (E_R + N_R > E_C + N_C) ? (E_R + N_R) : (E_C + N_C);
    float* exb = alloc(maxM);
    (void)ws_size; (void)n_in; (void)out_size;

    auto gat = [&](const float* x, int d_in_dim, const int* ei, int E, int n,
                   const float* W, const float* as_, const float* ad_, const float* b,
                   float* h, float* agg, float* es, float* ed, unsigned* m, float* den) {
        k_linear<<<n, HID, 0, stream>>>(x, W, as_, ad_, h, es, ed, d_in_dim);
        k_init_md<<<cdiv(n, 256), 256, 0, stream>>>(m, den, n);
        hipMemsetAsync(agg, 0, (size_t)n * HID * sizeof(float), stream);
        int M = E + n;
        k_edge_max<<<cdiv(M, 256), 256, 0, stream>>>(ei, E, n, es, ed, m);
        k_edge_ex<<<cdiv(M, 256), 256, 0, stream>>>(ei, E, n, es, ed, m, den, exb);
        k_edge_agg<<<cdiv((long long)M * HID, 256), 256, 0, stream>>>(ei, E, n, exb, den, h, agg);
        k_bias_relu<<<cdiv((long long)n * HID, 256), 256, 0, stream>>>(agg, b, n * HID);
    };

    gat(x_r, 6, ei_r, E_R, N_R, W_r1, as_r1, ad_r1, b_r1, r_h, r_agg, r_es, r_ed, r_m, r_den);
    gat(r_agg, HID, ei_r, E_R, N_R, W_r2, as_r2, ad_r2, b_r2, r_h, r_agg, r_es, r_ed, r_m, r_den);
    gat(x_c, 6, ei_c, E_C, N_C, W_c1, as_c1, ad_c1, b_c1, c_h, c_agg, c_es, c_ed, c_m, c_den);
    gat(c_agg, HID, ei_c, E_C, N_C, W_c2, as_c2, ad_c2, b_c2, c_h, c_agg, c_es, c_ed, c_m, c_den);

    // KNN: f16 convert + norms
    hipMemsetAsync(pooled, 0, (size_t)N_R * HID * sizeof(float), stream);
    hipMemsetAsync(cnt, 0, (size_t)N_R * sizeof(float), stream);
    k_norm_split<<<N_R, HID, 0, stream>>>(r_agg, nr2, hr2, 1);
    k_norm_split<<<N_C, HID, 0, stream>>>(c_agg, exb /*dummy*/, hc2, 0);

    // MFMA candidate scan
    int RS = cdiv(N_R, CSPLIT * 64) * 64;
    dim3 sgrid(cdiv(N_C, 128), CSPLIT);
    k_knn_scan<<<sgrid, 256, 0, stream>>>(hr2, hc2, nr2, N_C, N_R, RS, cand_i);

    // exact rerank + pooling
    k_rerank<<<N_C, HID, 0, stream>>>(cand_i, c_agg, r_agg, nr2, N_R, pooled, cnt);

    // decode
    k_decode<<<cdiv(N_R, 4), 256, 0, stream>>>(r_agg, pooled, cnt, W_dec, b_dec, out, N_R);
}

// Round 5
// 834.851 us; speedup vs baseline: 10.3165x; 1.2710x over previous
//
#include <hip/hip_runtime.h>
#include <hip/hip_bf16.h>

#define HID 128
#define NEG_SLOPE 0.2f
#define CSPLIT 6
#define KNN_CB 64

typedef _Float16 f16x8 __attribute__((ext_vector_type(8)));
typedef float f32x4 __attribute__((ext_vector_type(4)));

// ---------- helpers ----------
__device__ __forceinline__ bool cand_lt(float d1, int i1, float d2, int i2) {
    return d1 < d2 || (d1 == d2 && i1 < i2);
}
__device__ __forceinline__ void ins4(float s, int r, float bd[4], int bi[4]) {
    if (!cand_lt(s, r, bd[3], bi[3])) return;
    if (cand_lt(s, r, bd[0], bi[0])) {
        bd[3]=bd[2];bi[3]=bi[2]; bd[2]=bd[1];bi[2]=bi[1]; bd[1]=bd[0];bi[1]=bi[0]; bd[0]=s;bi[0]=r;
    } else if (cand_lt(s, r, bd[1], bi[1])) {
        bd[3]=bd[2];bi[3]=bi[2]; bd[2]=bd[1];bi[2]=bi[1]; bd[1]=s;bi[1]=r;
    } else if (cand_lt(s, r, bd[2], bi[2])) {
        bd[3]=bd[2];bi[3]=bi[2]; bd[2]=s;bi[2]=r;
    } else {
        bd[3]=s;bi[3]=r;
    }
}
__device__ __forceinline__ void ins3(float s, int r, float fd[3], int fi[3]) {
    if (!cand_lt(s, r, fd[2], fi[2])) return;
    if (cand_lt(s, r, fd[0], fi[0])) {
        fd[2]=fd[1];fi[2]=fi[1]; fd[1]=fd[0];fi[1]=fi[0]; fd[0]=s;fi[0]=r;
    } else if (cand_lt(s, r, fd[1], fi[1])) {
        fd[2]=fd[1];fi[2]=fi[1]; fd[1]=s;fi[1]=r;
    } else {
        fd[2]=s;fi[2]=r;
    }
}

// ---------- CSR build ----------
__global__ void k_deg(const int* __restrict__ ei, int E, int n, int* __restrict__ deg) {
    int i = blockIdx.x * blockDim.x + threadIdx.x;
    if (i >= E + n) return;
    int d = (i < E) ? ei[E + i] : i - E;
    atomicAdd(&deg[d], 1);
}

// single-block exclusive scan: off[0..n], cursor copy
__global__ void k_scan(const int* __restrict__ deg, int* __restrict__ off,
                       int* __restrict__ cursor, int n) {
    __shared__ int carry;
    __shared__ int buf[256];
    int t = threadIdx.x;
    if (t == 0) carry = 0;
    __syncthreads();
    for (int base = 0; base < n; base += 256) {
        int i = base + t;
        int v = (i < n) ? deg[i] : 0;
        buf[t] = v;
        __syncthreads();
        for (int o = 1; o < 256; o <<= 1) {
            int add = (t >= o) ? buf[t - o] : 0;
            __syncthreads();
            buf[t] += add;
            __syncthreads();
        }
        int excl = carry + buf[t] - v;
        if (i < n) { off[i] = excl; cursor[i] = excl; }
        __syncthreads();
        if (t == 255) carry += buf[255];
        __syncthreads();
    }
    if (t == 0) off[n] = carry;
}

__global__ void k_scatter(const int* __restrict__ ei, int E, int n,
                          int* __restrict__ cursor, int* __restrict__ csr) {
    int i = blockIdx.x * blockDim.x + threadIdx.x;
    if (i >= E + n) return;
    int s, d;
    if (i < E) { s = ei[i]; d = ei[E + i]; } else { s = d = i - E; }
    int pos = atomicAdd(&cursor[d], 1);
    csr[pos] = s;
}

// ---------- linear: 4 nodes per block (128 thr), W reads shared ----------
__global__ __launch_bounds__(128) void k_linear(
    const float* __restrict__ x, const float* __restrict__ W,
    const float* __restrict__ a_src, const float* __restrict__ a_dst,
    float* __restrict__ h, float* __restrict__ es, float* __restrict__ ed,
    int d_in, int n) {
    int n0 = blockIdx.x * 4;
    int t = threadIdx.x;
    int w = t >> 6, lane = t & 63;
    __shared__ float xs[4][HID];
    __shared__ float p1[2], p2[2];
#pragma unroll
    for (int u = 0; u < 4; ++u) {
        int node = n0 + u;
        if (t < d_in) xs[u][t] = (node < n) ? x[(size_t)node * d_in + t] : 0.f;
    }
    __syncthreads();
    float acc[4] = {0.f, 0.f, 0.f, 0.f};
    for (int k = 0; k < d_in; ++k) {
        float wv = W[k * HID + t];
#pragma unroll
        for (int u = 0; u < 4; ++u) acc[u] += xs[u][k] * wv;
    }
    float asv = a_src[t], adv = a_dst[t];
    for (int u = 0; u < 4; ++u) {
        int node = n0 + u;
        if (node >= n) break;                     // uniform across block
        h[(size_t)node * HID + t] = acc[u];
        float v1 = acc[u] * asv, v2 = acc[u] * adv;
#pragma unroll
        for (int o = 32; o > 0; o >>= 1) { v1 += __shfl_xor(v1, o); v2 += __shfl_xor(v2, o); }
        if (lane == 0) { p1[w] = v1; p2[w] = v2; }
        __syncthreads();
        if (t == 0) { es[node] = p1[0] + p1[1]; ed[node] = p2[0] + p2[1]; }
        __syncthreads();
    }
}

// ---------- fused GAT aggregation over CSR (wave per dst node) ----------
__global__ __launch_bounds__(256) void k_gat_csr(
    const int* __restrict__ off, const int* __restrict__ csr,
    const float* __restrict__ es, const float* __restrict__ ed,
    const float* __restrict__ h, const float* __restrict__ b,
    float* __restrict__ agg, int n) {
    int node = blockIdx.x * 4 + (threadIdx.x >> 6);
    int lane = threadIdx.x & 63;
    if (node >= n) return;                        // wave-uniform
    int beg = off[node], end = off[node + 1];
    float edd = ed[node];
    // pass 1: segment max (lane-parallel)
    float m = -INFINITY;
    for (int j = beg + lane; j < end; j += 64) {
        int s = csr[j];
        float e = es[s] + edd;
        e = e > 0.f ? e : NEG_SLOPE * e;
        m = fmaxf(m, e);
    }
#pragma unroll
    for (int o = 32; o > 0; o >>= 1) m = fmaxf(m, __shfl_xor(m, o));
    // pass 2: unnormalized accumulate + denominator (serial edges, 2 dims/lane)
    float den = 0.f, a0 = 0.f, a1 = 0.f;
    int s = (beg < end) ? csr[beg] : 0;
    for (int j = beg; j < end; ++j) {
        int sn = (j + 1 < end) ? csr[j + 1] : 0;
        float e = es[s] + edd;
        e = e > 0.f ? e : NEG_SLOPE * e;
        float ex = expf(e - m);
        den += ex;
        a0 += ex * h[(size_t)s * HID + lane];
        a1 += ex * h[(size_t)s * HID + 64 + lane];
        s = sn;
    }
    float inv = 1.f / fmaxf(den, 1e-16f);
    float v0 = a0 * inv + b[lane];
    float v1 = a1 * inv + b[64 + lane];
    agg[(size_t)node * HID + lane] = v0 > 0.f ? v0 : 0.f;
    agg[(size_t)node * HID + 64 + lane] = v1 > 0.f ? v1 : 0.f;
}

// norm (optional) + fp32 -> f16 split
__global__ void k_norm_split(const float* __restrict__ h, float* __restrict__ n2,
                             _Float16* __restrict__ h2, int do_norm) {
    int node = blockIdx.x;
    int t = threadIdx.x;
    float v = h[(long long)node * HID + t];
    h2[(long long)node * HID + t] = (_Float16)v;
    if (do_norm) {
        __shared__ float s[HID];
        s[t] = v * v;
        __syncthreads();
        for (int off = 64; off > 0; off >>= 1) {
            if (t < off) s[t] += s[t + off];
            __syncthreads();
        }
        if (t == 0) n2[node] = s[0];
    }
}

// ---------- MFMA KNN scan ----------
// grid (ceil(N_C/64), CSPLIT), 256 thr = 4 waves; wave owns 16 colliders
// (B-frags in regs, full K=128). Resting rows streamed via global_load_lds
// into double-buffered LDS; source slot pre-XOR'd so LDS content is swizzled
// (rule #21: linear dest + inverse-swizzled source + swizzled read).
__global__ __launch_bounds__(256) void k_knn_scan(
    const _Float16* __restrict__ hr2, const _Float16* __restrict__ hc2,
    const float* __restrict__ nr2, int n_c, int n_r, int rs_chunk,
    int* __restrict__ cand_i) {
    __shared__ _Float16 lds[2][64 * HID];
    int t = threadIdx.x, w = t >> 6, lane = t & 63;
    int li = lane & 15, q = lane >> 4;
    int c0 = blockIdx.x * KNN_CB;
    int split = blockIdx.y;
    int rbeg = split * rs_chunk;
    int rows = min(rs_chunk, n_r - rbeg);
    int rend = rbeg + rows;

    if (rows <= 0) {
        int c = c0 + w * 16 + li;
        if (c < n_c) {
            size_t base = ((size_t)(c * CSPLIT + split) * 4 + q) * 4;
            for (int k = 0; k < 4; ++k) cand_i[base + k] = 0x7fffffff;
        }
        return;
    }

    // B fragments: collider col = li, k = ks*32 + q*8 .. +7
    f16x8 bf[4];
    {
        int c = c0 + w * 16 + li;
        int cc = min(c, n_c - 1);
#pragma unroll
        for (int ks = 0; ks < 4; ++ks)
            bf[ks] = *(const f16x8*)(hc2 + (size_t)cc * HID + ks * 32 + q * 8);
    }

    float bd[4]; int bi[4];
#pragma unroll
    for (int k = 0; k < 4; ++k) { bd[k] = INFINITY; bi[k] = 0x7fffffff; }

    int nch = (rows + 63) >> 6;

    // wave w stages rows w*16 .. w*16+15 (4 calls x 1KB). Lane l of call j:
    // LDS (row = w*16+j*4 + (l>>4), slot = l&15); global src slot XOR'd by row&7.
    auto STAGE = [&](int bsel, int R) {
#pragma unroll
        for (int j = 0; j < 4; ++j) {
            int row = w * 16 + j * 4 + q;
            int gr = min(R + row, n_r - 1);
            int sslot = li ^ (row & 7);
            const _Float16* src = hr2 + (size_t)gr * HID + sslot * 8;
            _Float16* dst = &lds[bsel][(w * 16 + j * 4) * HID];  // wave-uniform
            __builtin_amdgcn_global_load_lds(
                (const __attribute__((address_space(1))) void*)src,
                (__attribute__((address_space(3))) void*)dst, 16, 0, 0);
        }
    };

    STAGE(0, rbeg);
    __syncthreads();

    for (int ch = 0; ch < nch; ++ch) {
        int cur = ch & 1;
        if (ch + 1 < nch) STAGE(cur ^ 1, rbeg + (ch + 1) * 64);  // prefetch (drained by barrier)
        int R = rbeg + ch * 64;
        int rows_rem = rend - R;
        const _Float16* buf = lds[cur];
#pragma unroll
        for (int tt = 0; tt < 4; ++tt) {
            int br = tt * 16;
            if (br < rows_rem) {
                f32x4 a0 = {0.f, 0.f, 0.f, 0.f};
                int lr = br + li;
                int sw = lr & 7;
#pragma unroll
                for (int ks = 0; ks < 4; ++ks) {
                    f16x8 af = *(const f16x8*)(&buf[lr * HID + (((ks * 4 + q) ^ sw) << 3)]);
                    a0 = __builtin_amdgcn_mfma_f32_16x16x32_f16(af, bf[ks], a0, 0, 0, 0);
                }
                int r_base = R + br + q * 4;
                float4 nrv = *(const float4*)(nr2 + r_base);
                float sv[4] = {nrv.x, nrv.y, nrv.z, nrv.w};
#pragma unroll
                for (int i = 0; i < 4; ++i) {
                    int r = r_base + i;
                    if (r < rend) ins4(sv[i] - 2.f * a0[i], r, bd, bi);
                }
            }
        }
        __syncthreads();
    }

    {
        int c = c0 + w * 16 + li;
        if (c < n_c) {
            size_t base = ((size_t)(c * CSPLIT + split) * 4 + q) * 4;
#pragma unroll
            for (int k = 0; k < 4; ++k) cand_i[base + k] = bi[k];
        }
    }
}

// ---------- exact rerank + pooling ----------
__global__ __launch_bounds__(128) void k_rerank(
    const int* __restrict__ cand_i, const float* __restrict__ hc,
    const float* __restrict__ hr, const float* __restrict__ nr2,
    int n_r, float* __restrict__ pooled, float* __restrict__ cnt) {
    int c = blockIdx.x;
    int t = threadIdx.x, w = t >> 6, lane = t & 63;
    __shared__ float wd[2][3];
    __shared__ int wi[2][3];
    __shared__ int bidx[3];
    float hc0 = hc[(size_t)c * HID + lane];
    float hc1 = hc[(size_t)c * HID + 64 + lane];
    float fd[3] = {INFINITY, INFINITY, INFINITY};
    int fi[3] = {0x7fffffff, 0x7fffffff, 0x7fffffff};
    for (int jj = 0; jj < CSPLIT * 16 / 2; ++jj) {
        int j = w * (CSPLIT * 16 / 2) + jj;
        int r = cand_i[(size_t)c * (CSPLIT * 16) + j];
        if (r < 0 || r >= n_r) continue;
        float p = hc0 * hr[(size_t)r * HID + lane] + hc1 * hr[(size_t)r * HID + 64 + lane];
#pragma unroll
        for (int o = 1; o < 64; o <<= 1) p += __shfl_xor(p, o);
        float s = nr2[r] - 2.f * p;
        ins3(s, r, fd, fi);
    }
    if (lane == 0) {
#pragma unroll
        for (int k = 0; k < 3; ++k) { wd[w][k] = fd[k]; wi[w][k] = fi[k]; }
    }
    __syncthreads();
    if (t == 0) {
        float gd[3] = {INFINITY, INFINITY, INFINITY};
        int gi[3] = {0x7fffffff, 0x7fffffff, 0x7fffffff};
        for (int ww = 0; ww < 2; ++ww)
            for (int k = 0; k < 3; ++k) ins3(wd[ww][k], wi[ww][k], gd, gi);
        bidx[0] = gi[0]; bidx[1] = gi[1]; bidx[2] = gi[2];
    }
    __syncthreads();
    float v = hc[(size_t)c * HID + t];
#pragma unroll
    for (int k = 0; k < 3; ++k) {
        int bx = bidx[k];
        if (bx >= 0 && bx < n_r) {
            atomicAdd(&pooled[(size_t)bx * HID + t], v);
            if (t == 0) atomicAdd(&cnt[bx], 1.0f);
        }
    }
}

// one wave per resting node
__global__ void k_decode(const float* __restrict__ hr, const float* __restrict__ pooled,
                         const float* __restrict__ cnt, const float* __restrict__ Wd,
                         const float* __restrict__ bd, float* __restrict__ out, int n) {
    int node = blockIdx.x * (blockDim.x / 64) + (threadIdx.x >> 6);
    int lane = threadIdx.x & 63;
    if (node >= n) return;
    float c = fmaxf(cnt[node], 1.0f);
    float a0 = 0.f, a1 = 0.f, a2 = 0.f;
    for (int k = lane; k < HID; k += 64) {
        float v = hr[(long long)node * HID + k];
        a0 += v * Wd[k * 3 + 0];
        a1 += v * Wd[k * 3 + 1];
        a2 += v * Wd[k * 3 + 2];
        float p = pooled[(long long)node * HID + k] / c;
        a0 += p * Wd[(HID + k) * 3 + 0];
        a1 += p * Wd[(HID + k) * 3 + 1];
        a2 += p * Wd[(HID + k) * 3 + 2];
    }
    for (int off = 32; off > 0; off >>= 1) {
        a0 += __shfl_down(a0, off);
        a1 += __shfl_down(a1, off);
        a2 += __shfl_down(a2, off);
    }
    if (lane == 0) {
        out[(long long)node * 3 + 0] = a0 + bd[0];
        out[(long long)node * 3 + 1] = a1 + bd[1];
        out[(long long)node * 3 + 2] = a2 + bd[2];
    }
}

// ---------- launch ----------
static inline int cdiv(long long a, int b) { return (int)((a + b - 1) / b); }

extern "C" void kernel_launch(void* const* d_in, const int* in_sizes, int n_in,
                              void* d_out, int out_size, void* d_ws, size_t ws_size,
                              hipStream_t stream) {
    const float* x_r = (const float*)d_in[0];
    const float* x_c = (const float*)d_in[1];
    const int* ei_r = (const int*)d_in[2];
    const int* ei_c = (const int*)d_in[3];
    const float* W_r1 = (const float*)d_in[5];
    const float* as_r1 = (const float*)d_in[6];
    const float* ad_r1 = (const float*)d_in[7];
    const float* b_r1 = (const float*)d_in[8];
    const float* W_r2 = (const float*)d_in[9];
    const float* as_r2 = (const float*)d_in[10];
    const float* ad_r2 = (const float*)d_in[11];
    const float* b_r2 = (const float*)d_in[12];
    const float* W_c1 = (const float*)d_in[13];
    const float* as_c1 = (const float*)d_in[14];
    const float* ad_c1 = (const float*)d_in[15];
    const float* b_c1 = (const float*)d_in[16];
    const float* W_c2 = (const float*)d_in[17];
    const float* as_c2 = (const float*)d_in[18];
    const float* ad_c2 = (const float*)d_in[19];
    const float* b_c2 = (const float*)d_in[20];
    const float* W_dec = (const float*)d_in[21];
    const float* b_dec = (const float*)d_in[22];
    float* out = (float*)d_out;

    const int N_R = in_sizes[0] / 6;
    const int N_C = in_sizes[1] / 6;
    const int E_R = in_sizes[2] / 2;
    const int E_C = in_sizes[3] / 2;

    float* ws = (float*)d_ws;
    size_t off = 0;
    auto alloc = [&](size_t nf) {
        float* p = ws + off;
        off += (nf + 3) & ~(size_t)3;
        return p;
    };
    float* r_h    = alloc((size_t)N_R * HID);
    float* r_agg  = alloc((size_t)N_R * HID);
    float* c_h    = alloc((size_t)N_C * HID);
    float* c_agg  = alloc((size_t)N_C * HID);
    float* pooled = alloc((size_t)N_R * HID);
    float* r_es = alloc(N_R);
    float* r_ed = alloc(N_R);
    float* c_es = alloc(N_C);
    float* c_ed = alloc(N_C);
    float* cnt = alloc(N_R);
    float* nr2 = alloc((size_t)N_R + 64);
    _Float16* hr2 = (_Float16*)alloc((size_t)N_R * HID / 2);
    _Float16* hc2 = (_Float16*)alloc((size_t)N_C * HID / 2);
    int* cand_i = (int*)alloc((size_t)N_C * CSPLIT * 16);
    // CSR (resting)
    int* r_deg = (int*)alloc(N_R);
    int* r_off = (int*)alloc((size_t)N_R + 1);
    int* r_cur = (int*)alloc(N_R);
    int* r_csr = (int*)alloc((size_t)E_R + N_R);
    // CSR (collider)
    int* c_deg = (int*)alloc(N_C);
    int* c_off = (int*)alloc((size_t)N_C + 1);
    int* c_cur = (int*)alloc(N_C);
    int* c_csr = (int*)alloc((size_t)E_C + N_C);
    (void)ws_size; (void)n_in; (void)out_size;

    auto build_csr = [&](const int* ei, int E, int n, int* deg, int* offp, int* cur, int* csr) {
        hipMemsetAsync(deg, 0, (size_t)n * sizeof(int), stream);
        k_deg<<<cdiv(E + n, 256), 256, 0, stream>>>(ei, E, n, deg);
        k_scan<<<1, 256, 0, stream>>>(deg, offp, cur, n);
        k_scatter<<<cdiv(E + n, 256), 256, 0, stream>>>(ei, E, n, cur, csr);
    };
    auto gat = [&](const float* x, int d_in_dim, int n, const int* offp, const int* csr,
                   const float* W, const float* as_, const float* ad_, const float* b,
                   float* h, float* es, float* ed, float* agg) {
        k_linear<<<cdiv(n, 4), 128, 0, stream>>>(x, W, as_, ad_, h, es, ed, d_in_dim, n);
        k_gat_csr<<<cdiv(n, 4), 256, 0, stream>>>(offp, csr, es, ed, h, b, agg, n);
    };

    // resting branch
    build_csr(ei_r, E_R, N_R, r_deg, r_off, r_cur, r_csr);
    gat(x_r, 6, N_R, r_off, r_csr, W_r1, as_r1, ad_r1, b_r1, r_h, r_es, r_ed, r_agg);
    gat(r_agg, HID, N_R, r_off, r_csr, W_r2, as_r2, ad_r2, b_r2, r_h, r_es, r_ed, r_agg);
    // collider branch
    build_csr(ei_c, E_C, N_C, c_deg, c_off, c_cur, c_csr);
    gat(x_c, 6, N_C, c_off, c_csr, W_c1, as_c1, ad_c1, b_c1, c_h, c_es, c_ed, c_agg);
    gat(c_agg, HID, N_C, c_off, c_csr, W_c2, as_c2, ad_c2, b_c2, c_h, c_es, c_ed, c_agg);

    // KNN: f16 convert + norms
    hipMemsetAsync(pooled, 0, (size_t)N_R * HID * sizeof(float), stream);
    hipMemsetAsync(cnt, 0, (size_t)N_R * sizeof(float), stream);
    k_norm_split<<<N_R, HID, 0, stream>>>(r_agg, nr2, hr2, 1);
    k_norm_split<<<N_C, HID, 0, stream>>>(c_agg, nr2, hc2, 0);

    // MFMA candidate scan
    int RS = cdiv(N_R, CSPLIT * 64) * 64;
    dim3 sgrid(cdiv(N_C, KNN_CB), CSPLIT);
    k_knn_scan<<<sgrid, 256, 0, stream>>>(hr2, hc2, nr2, N_C, N_R, RS, cand_i);

    // exact rerank + pooling
    k_rerank<<<N_C, HID, 0, stream>>>(cand_i, c_agg, r_agg, nr2, N_R, pooled, cnt);

    // decode
    k_decode<<<cdiv(N_R, 4), 256, 0, stream>>>(r_agg, pooled, cnt, W_dec, b_dec, out, N_R);
}

// Round 6
// 825.421 us; speedup vs baseline: 10.4343x; 1.0114x over previous
//
#include <hip/hip_runtime.h>
#include <hip/hip_bf16.h>

#define HID 128
#define NEG_SLOPE 0.2f
#define CSPLIT 6
#define KNN_CB 64

typedef _Float16 f16x8 __attribute__((ext_vector_type(8)));
typedef float f32x4 __attribute__((ext_vector_type(4)));

// ---------- helpers ----------
__device__ __forceinline__ bool cand_lt(float d1, int i1, float d2, int i2) {
    return d1 < d2 || (d1 == d2 && i1 < i2);
}
__device__ __forceinline__ void ins4(float s, int r, float bd[4], int bi[4]) {
    if (!cand_lt(s, r, bd[3], bi[3])) return;
    if (cand_lt(s, r, bd[0], bi[0])) {
        bd[3]=bd[2];bi[3]=bi[2]; bd[2]=bd[1];bi[2]=bi[1]; bd[1]=bd[0];bi[1]=bi[0]; bd[0]=s;bi[0]=r;
    } else if (cand_lt(s, r, bd[1], bi[1])) {
        bd[3]=bd[2];bi[3]=bi[2]; bd[2]=bd[1];bi[2]=bi[1]; bd[1]=s;bi[1]=r;
    } else if (cand_lt(s, r, bd[2], bi[2])) {
        bd[3]=bd[2];bi[3]=bi[2]; bd[2]=s;bi[2]=r;
    } else {
        bd[3]=s;bi[3]=r;
    }
}
__device__ __forceinline__ void ins3(float s, int r, float fd[3], int fi[3]) {
    if (!cand_lt(s, r, fd[2], fi[2])) return;
    if (cand_lt(s, r, fd[0], fi[0])) {
        fd[2]=fd[1];fi[2]=fi[1]; fd[1]=fd[0];fi[1]=fi[0]; fd[0]=s;fi[0]=r;
    } else if (cand_lt(s, r, fd[1], fi[1])) {
        fd[2]=fd[1];fi[2]=fi[1]; fd[1]=s;fi[1]=r;
    } else {
        fd[2]=s;fi[2]=r;
    }
}

// ---------- CSR build ----------
__global__ void k_deg(const int* __restrict__ ei, int E, int n, int* __restrict__ deg) {
    int i = blockIdx.x * blockDim.x + threadIdx.x;
    if (i >= E + n) return;
    int d = (i < E) ? ei[E + i] : i - E;
    atomicAdd(&deg[d], 1);
}

// single-block exclusive scan: off[0..n], cursor copy
__global__ void k_scan(const int* __restrict__ deg, int* __restrict__ off,
                       int* __restrict__ cursor, int n) {
    __shared__ int carry;
    __shared__ int buf[256];
    int t = threadIdx.x;
    if (t == 0) carry = 0;
    __syncthreads();
    for (int base = 0; base < n; base += 256) {
        int i = base + t;
        int v = (i < n) ? deg[i] : 0;
        buf[t] = v;
        __syncthreads();
        for (int o = 1; o < 256; o <<= 1) {
            int add = (t >= o) ? buf[t - o] : 0;
            __syncthreads();
            buf[t] += add;
            __syncthreads();
        }
        int excl = carry + buf[t] - v;
        if (i < n) { off[i] = excl; cursor[i] = excl; }
        __syncthreads();
        if (t == 255) carry += buf[255];
        __syncthreads();
    }
    if (t == 0) off[n] = carry;
}

__global__ void k_scatter(const int* __restrict__ ei, int E, int n,
                          int* __restrict__ cursor, int* __restrict__ csr) {
    int i = blockIdx.x * blockDim.x + threadIdx.x;
    if (i >= E + n) return;
    int s, d;
    if (i < E) { s = ei[i]; d = ei[E + i]; } else { s = d = i - E; }
    int pos = atomicAdd(&cursor[d], 1);
    csr[pos] = s;
}

// ---------- linear: 4 nodes per block (128 thr), W reads shared ----------
__global__ __launch_bounds__(128) void k_linear(
    const float* __restrict__ x, const float* __restrict__ W,
    const float* __restrict__ a_src, const float* __restrict__ a_dst,
    float* __restrict__ h, float* __restrict__ es, float* __restrict__ ed,
    int d_in, int n) {
    int n0 = blockIdx.x * 4;
    int t = threadIdx.x;
    int w = t >> 6, lane = t & 63;
    __shared__ float xs[4][HID];
    __shared__ float p1[2], p2[2];
#pragma unroll
    for (int u = 0; u < 4; ++u) {
        int node = n0 + u;
        if (t < d_in) xs[u][t] = (node < n) ? x[(size_t)node * d_in + t] : 0.f;
    }
    __syncthreads();
    float acc[4] = {0.f, 0.f, 0.f, 0.f};
    for (int k = 0; k < d_in; ++k) {
        float wv = W[k * HID + t];
#pragma unroll
        for (int u = 0; u < 4; ++u) acc[u] += xs[u][k] * wv;
    }
    float asv = a_src[t], adv = a_dst[t];
    for (int u = 0; u < 4; ++u) {
        int node = n0 + u;
        if (node >= n) break;                     // uniform across block
        h[(size_t)node * HID + t] = acc[u];
        float v1 = acc[u] * asv, v2 = acc[u] * adv;
#pragma unroll
        for (int o = 32; o > 0; o >>= 1) { v1 += __shfl_xor(v1, o); v2 += __shfl_xor(v2, o); }
        if (lane == 0) { p1[w] = v1; p2[w] = v2; }
        __syncthreads();
        if (t == 0) { es[node] = p1[0] + p1[1]; ed[node] = p2[0] + p2[1]; }
        __syncthreads();
    }
}

// ---------- fused GAT aggregation over CSR (wave per dst node) ----------
__global__ __launch_bounds__(256) void k_gat_csr(
    const int* __restrict__ off, const int* __restrict__ csr,
    const float* __restrict__ es, const float* __restrict__ ed,
    const float* __restrict__ h, const float* __restrict__ b,
    float* __restrict__ agg, int n) {
    int node = blockIdx.x * 4 + (threadIdx.x >> 6);
    int lane = threadIdx.x & 63;
    if (node >= n) return;                        // wave-uniform
    int beg = off[node], end = off[node + 1];
    float edd = ed[node];
    // pass 1: segment max (lane-parallel)
    float m = -INFINITY;
    for (int j = beg + lane; j < end; j += 64) {
        int s = csr[j];
        float e = es[s] + edd;
        e = e > 0.f ? e : NEG_SLOPE * e;
        m = fmaxf(m, e);
    }
#pragma unroll
    for (int o = 32; o > 0; o >>= 1) m = fmaxf(m, __shfl_xor(m, o));
    // pass 2: unnormalized accumulate + denominator (serial edges, 2 dims/lane)
    float den = 0.f, a0 = 0.f, a1 = 0.f;
    int s = (beg < end) ? csr[beg] : 0;
    for (int j = beg; j < end; ++j) {
        int sn = (j + 1 < end) ? csr[j + 1] : 0;
        float e = es[s] + edd;
        e = e > 0.f ? e : NEG_SLOPE * e;
        float ex = expf(e - m);
        den += ex;
        a0 += ex * h[(size_t)s * HID + lane];
        a1 += ex * h[(size_t)s * HID + 64 + lane];
        s = sn;
    }
    float inv = 1.f / fmaxf(den, 1e-16f);
    float v0 = a0 * inv + b[lane];
    float v1 = a1 * inv + b[64 + lane];
    agg[(size_t)node * HID + lane] = v0 > 0.f ? v0 : 0.f;
    agg[(size_t)node * HID + 64 + lane] = v1 > 0.f ? v1 : 0.f;
}

// norm (optional) + fp32 -> f16 split
__global__ void k_norm_split(const float* __restrict__ h, float* __restrict__ n2,
                             _Float16* __restrict__ h2, int do_norm) {
    int node = blockIdx.x;
    int t = threadIdx.x;
    float v = h[(long long)node * HID + t];
    h2[(long long)node * HID + t] = (_Float16)v;
    if (do_norm) {
        __shared__ float s[HID];
        s[t] = v * v;
        __syncthreads();
        for (int off = 64; off > 0; off >>= 1) {
            if (t < off) s[t] += s[t + off];
            __syncthreads();
        }
        if (t == 0) n2[node] = s[0];
    }
}

// ---------- MFMA KNN scan (unchanged from round 5) ----------
__global__ __launch_bounds__(256) void k_knn_scan(
    const _Float16* __restrict__ hr2, const _Float16* __restrict__ hc2,
    const float* __restrict__ nr2, int n_c, int n_r, int rs_chunk,
    int* __restrict__ cand_i) {
    __shared__ _Float16 lds[2][64 * HID];
    int t = threadIdx.x, w = t >> 6, lane = t & 63;
    int li = lane & 15, q = lane >> 4;
    int c0 = blockIdx.x * KNN_CB;
    int split = blockIdx.y;
    int rbeg = split * rs_chunk;
    int rows = min(rs_chunk, n_r - rbeg);
    int rend = rbeg + rows;

    if (rows <= 0) {
        int c = c0 + w * 16 + li;
        if (c < n_c) {
            size_t base = ((size_t)(c * CSPLIT + split) * 4 + q) * 4;
            for (int k = 0; k < 4; ++k) cand_i[base + k] = 0x7fffffff;
        }
        return;
    }

    // B fragments: collider col = li, k = ks*32 + q*8 .. +7
    f16x8 bf[4];
    {
        int c = c0 + w * 16 + li;
        int cc = min(c, n_c - 1);
#pragma unroll
        for (int ks = 0; ks < 4; ++ks)
            bf[ks] = *(const f16x8*)(hc2 + (size_t)cc * HID + ks * 32 + q * 8);
    }

    float bd[4]; int bi[4];
#pragma unroll
    for (int k = 0; k < 4; ++k) { bd[k] = INFINITY; bi[k] = 0x7fffffff; }

    int nch = (rows + 63) >> 6;

    auto STAGE = [&](int bsel, int R) {
#pragma unroll
        for (int j = 0; j < 4; ++j) {
            int row = w * 16 + j * 4 + q;
            int gr = min(R + row, n_r - 1);
            int sslot = li ^ (row & 7);
            const _Float16* src = hr2 + (size_t)gr * HID + sslot * 8;
            _Float16* dst = &lds[bsel][(w * 16 + j * 4) * HID];  // wave-uniform
            __builtin_amdgcn_global_load_lds(
                (const __attribute__((address_space(1))) void*)src,
                (__attribute__((address_space(3))) void*)dst, 16, 0, 0);
        }
    };

    STAGE(0, rbeg);
    __syncthreads();

    for (int ch = 0; ch < nch; ++ch) {
        int cur = ch & 1;
        if (ch + 1 < nch) STAGE(cur ^ 1, rbeg + (ch + 1) * 64);  // prefetch
        int R = rbeg + ch * 64;
        int rows_rem = rend - R;
        const _Float16* buf = lds[cur];
#pragma unroll
        for (int tt = 0; tt < 4; ++tt) {
            int br = tt * 16;
            if (br < rows_rem) {
                f32x4 a0 = {0.f, 0.f, 0.f, 0.f};
                int lr = br + li;
                int sw = lr & 7;
#pragma unroll
                for (int ks = 0; ks < 4; ++ks) {
                    f16x8 af = *(const f16x8*)(&buf[lr * HID + (((ks * 4 + q) ^ sw) << 3)]);
                    a0 = __builtin_amdgcn_mfma_f32_16x16x32_f16(af, bf[ks], a0, 0, 0, 0);
                }
                int r_base = R + br + q * 4;
                float4 nrv = *(const float4*)(nr2 + r_base);
                float sv[4] = {nrv.x, nrv.y, nrv.z, nrv.w};
#pragma unroll
                for (int i = 0; i < 4; ++i) {
                    int r = r_base + i;
                    if (r < rend) ins4(sv[i] - 2.f * a0[i], r, bd, bi);
                }
            }
        }
        __syncthreads();
    }

    {
        int c = c0 + w * 16 + li;
        if (c < n_c) {
            size_t base = ((size_t)(c * CSPLIT + split) * 4 + q) * 4;
#pragma unroll
            for (int k = 0; k < 4; ++k) cand_i[base + k] = bi[k];
        }
    }
}

// ---------- exact rerank + pooling: wave per collider, candidate per lane ----
// 96 candidates: lane l owns cand[l] and (l<32) cand[64+l]. Each lane computes
// its candidate's full 128-dim fp32 dot (float4 row gather x LDS broadcast of
// the collider row), then a 6-stage butterfly top-3 merge; identical (d,idx)
// tie-break as before.
__global__ __launch_bounds__(256) void k_rerank(
    const int* __restrict__ cand_i, const float* __restrict__ hc,
    const float* __restrict__ hr, const float* __restrict__ nr2,
    int n_c, int n_r, float* __restrict__ pooled, float* __restrict__ cnt) {
    __shared__ float hcs[4][HID];
    int t = threadIdx.x, w = t >> 6, lane = t & 63;
    int c = blockIdx.x * 4 + w;
    if (c >= n_c) return;                         // wave-uniform
    float hv0 = hc[(size_t)c * HID + lane];
    float hv1 = hc[(size_t)c * HID + 64 + lane];
    hcs[w][lane] = hv0;
    hcs[w][64 + lane] = hv1;
    asm volatile("s_waitcnt lgkmcnt(0)" ::: "memory");  // same-wave LDS visibility
    const float4* hc4 = (const float4*)hcs[w];
    const int* cbase = cand_i + (size_t)c * (CSPLIT * 16);
    int r1 = cbase[lane];
    int r2 = (lane < 32) ? cbase[64 + lane] : 0x7fffffff;
    bool v1 = (unsigned)r1 < (unsigned)n_r;
    bool v2 = (unsigned)r2 < (unsigned)n_r;
    const float4* row1 = (const float4*)(hr + (size_t)(v1 ? r1 : 0) * HID);
    const float4* row2 = (const float4*)(hr + (size_t)(v2 ? r2 : 0) * HID);
    float d1 = 0.f, d2 = 0.f;
#pragma unroll 8
    for (int k4 = 0; k4 < 32; ++k4) {
        float4 a = hc4[k4];
        float4 x1 = row1[k4];
        float4 x2 = row2[k4];
        d1 += a.x * x1.x + a.y * x1.y + a.z * x1.z + a.w * x1.w;
        d2 += a.x * x2.x + a.y * x2.y + a.z * x2.z + a.w * x2.w;
    }
    float fd[3] = {INFINITY, INFINITY, INFINITY};
    int fi[3] = {0x7fffffff, 0x7fffffff, 0x7fffffff};
    if (v1) ins3(nr2[r1] - 2.f * d1, r1, fd, fi);
    if (v2) ins3(nr2[r2] - 2.f * d2, r2, fd, fi);
#pragma unroll
    for (int o = 1; o < 64; o <<= 1) {
        float sd0 = __shfl_xor(fd[0], o), sd1 = __shfl_xor(fd[1], o), sd2 = __shfl_xor(fd[2], o);
        int si0 = __shfl_xor(fi[0], o), si1 = __shfl_xor(fi[1], o), si2 = __shfl_xor(fi[2], o);
        ins3(sd0, si0, fd, fi);
        ins3(sd1, si1, fd, fi);
        ins3(sd2, si2, fd, fi);
    }
#pragma unroll
    for (int q = 0; q < 3; ++q) {
        int b = fi[q];
        if (b >= 0 && b < n_r) {
            atomicAdd(&pooled[(size_t)b * HID + lane], hv0);
            atomicAdd(&pooled[(size_t)b * HID + 64 + lane], hv1);
            if (lane == 0) atomicAdd(&cnt[b], 1.0f);
        }
    }
}

// one wave per resting node
__global__ void k_decode(const float* __restrict__ hr, const float* __restrict__ pooled,
                         const float* __restrict__ cnt, const float* __restrict__ Wd,
                         const float* __restrict__ bd, float* __restrict__ out, int n) {
    int node = blockIdx.x * (blockDim.x / 64) + (threadIdx.x >> 6);
    int lane = threadIdx.x & 63;
    if (node >= n) return;
    float c = fmaxf(cnt[node], 1.0f);
    float a0 = 0.f, a1 = 0.f, a2 = 0.f;
    for (int k = lane; k < HID; k += 64) {
        float v = hr[(long long)node * HID + k];
        a0 += v * Wd[k * 3 + 0];
        a1 += v * Wd[k * 3 + 1];
        a2 += v * Wd[k * 3 + 2];
        float p = pooled[(long long)node * HID + k] / c;
        a0 += p * Wd[(HID + k) * 3 + 0];
        a1 += p * Wd[(HID + k) * 3 + 1];
        a2 += p * Wd[(HID + k) * 3 + 2];
    }
    for (int off = 32; off > 0; off >>= 1) {
        a0 += __shfl_down(a0, off);
        a1 += __shfl_down(a1, off);
        a2 += __shfl_down(a2, off);
    }
    if (lane == 0) {
        out[(long long)node * 3 + 0] = a0 + bd[0];
        out[(long long)node * 3 + 1] = a1 + bd[1];
        out[(long long)node * 3 + 2] = a2 + bd[2];
    }
}

// ---------- launch ----------
static inline int cdiv(long long a, int b) { return (int)((a + b - 1) / b); }

extern "C" void kernel_launch(void* const* d_in, const int* in_sizes, int n_in,
                              void* d_out, int out_size, void* d_ws, size_t ws_size,
                              hipStream_t stream) {
    const float* x_r = (const float*)d_in[0];
    const float* x_c = (const float*)d_in[1];
    const int* ei_r = (const int*)d_in[2];
    const int* ei_c = (const int*)d_in[3];
    const float* W_r1 = (const float*)d_in[5];
    const float* as_r1 = (const float*)d_in[6];
    const float* ad_r1 = (const float*)d_in[7];
    const float* b_r1 = (const float*)d_in[8];
    const float* W_r2 = (const float*)d_in[9];
    const float* as_r2 = (const float*)d_in[10];
    const float* ad_r2 = (const float*)d_in[11];
    const float* b_r2 = (const float*)d_in[12];
    const float* W_c1 = (const float*)d_in[13];
    const float* as_c1 = (const float*)d_in[14];
    const float* ad_c1 = (const float*)d_in[15];
    const float* b_c1 = (const float*)d_in[16];
    const float* W_c2 = (const float*)d_in[17];
    const float* as_c2 = (const float*)d_in[18];
    const float* ad_c2 = (const float*)d_in[19];
    const float* b_c2 = (const float*)d_in[20];
    const float* W_dec = (const float*)d_in[21];
    const float* b_dec = (const float*)d_in[22];
    float* out = (float*)d_out;

    const int N_R = in_sizes[0] / 6;
    const int N_C = in_sizes[1] / 6;
    const int E_R = in_sizes[2] / 2;
    const int E_C = in_sizes[3] / 2;

    float* ws = (float*)d_ws;
    size_t off = 0;
    auto alloc = [&](size_t nf) {
        float* p = ws + off;
        off += (nf + 3) & ~(size_t)3;
        return p;
    };
    float* r_h    = alloc((size_t)N_R * HID);
    float* r_agg  = alloc((size_t)N_R * HID);
    float* c_h    = alloc((size_t)N_C * HID);
    float* c_agg  = alloc((size_t)N_C * HID);
    float* pooled = alloc((size_t)N_R * HID);
    float* r_es = alloc(N_R);
    float* r_ed = alloc(N_R);
    float* c_es = alloc(N_C);
    float* c_ed = alloc(N_C);
    float* cnt = alloc(N_R);
    float* nr2 = alloc((size_t)N_R + 64);
    _Float16* hr2 = (_Float16*)alloc((size_t)N_R * HID / 2);
    _Float16* hc2 = (_Float16*)alloc((size_t)N_C * HID / 2);
    int* cand_i = (int*)alloc((size_t)N_C * CSPLIT * 16);
    // CSR (resting)
    int* r_deg = (int*)alloc(N_R);
    int* r_off = (int*)alloc((size_t)N_R + 1);
    int* r_cur = (int*)alloc(N_R);
    int* r_csr = (int*)alloc((size_t)E_R + N_R);
    // CSR (collider)
    int* c_deg = (int*)alloc(N_C);
    int* c_off = (int*)alloc((size_t)N_C + 1);
    int* c_cur = (int*)alloc(N_C);
    int* c_csr = (int*)alloc((size_t)E_C + N_C);
    (void)ws_size; (void)n_in; (void)out_size;

    auto build_csr = [&](const int* ei, int E, int n, int* deg, int* offp, int* cur, int* csr) {
        hipMemsetAsync(deg, 0, (size_t)n * sizeof(int), stream);
        k_deg<<<cdiv(E + n, 256), 256, 0, stream>>>(ei, E, n, deg);
        k_scan<<<1, 256, 0, stream>>>(deg, offp, cur, n);
        k_scatter<<<cdiv(E + n, 256), 256, 0, stream>>>(ei, E, n, cur, csr);
    };
    auto gat = [&](const float* x, int d_in_dim, int n, const int* offp, const int* csr,
                   const float* W, const float* as_, const float* ad_, const float* b,
                   float* h, float* es, float* ed, float* agg) {
        k_linear<<<cdiv(n, 4), 128, 0, stream>>>(x, W, as_, ad_, h, es, ed, d_in_dim, n);
        k_gat_csr<<<cdiv(n, 4), 256, 0, stream>>>(offp, csr, es, ed, h, b, agg, n);
    };

    // resting branch
    build_csr(ei_r, E_R, N_R, r_deg, r_off, r_cur, r_csr);
    gat(x_r, 6, N_R, r_off, r_csr, W_r1, as_r1, ad_r1, b_r1, r_h, r_es, r_ed, r_agg);
    gat(r_agg, HID, N_R, r_off, r_csr, W_r2, as_r2, ad_r2, b_r2, r_h, r_es, r_ed, r_agg);
    // collider branch
    build_csr(ei_c, E_C, N_C, c_deg, c_off, c_cur, c_csr);
    gat(x_c, 6, N_C, c_off, c_csr, W_c1, as_c1, ad_c1, b_c1, c_h, c_es, c_ed, c_agg);
    gat(c_agg, HID, N_C, c_off, c_csr, W_c2, as_c2, ad_c2, b_c2, c_h, c_es, c_ed, c_agg);

    // KNN: f16 convert + norms
    hipMemsetAsync(pooled, 0, (size_t)N_R * HID * sizeof(float), stream);
    hipMemsetAsync(cnt, 0, (size_t)N_R * sizeof(float), stream);
    k_norm_split<<<N_R, HID, 0, stream>>>(r_agg, nr2, hr2, 1);
    k_norm_split<<<N_C, HID, 0, stream>>>(c_agg, nr2, hc2, 0);

    // MFMA candidate scan
    int RS = cdiv(N_R, CSPLIT * 64) * 64;
    dim3 sgrid(cdiv(N_C, KNN_CB), CSPLIT);
    k_knn_scan<<<sgrid, 256, 0, stream>>>(hr2, hc2, nr2, N_C, N_R, RS, cand_i);

    // exact rerank + pooling (wave per collider)
    k_rerank<<<cdiv(N_C, 4), 256, 0, stream>>>(cand_i, c_agg, r_agg, nr2, N_C, N_R, pooled, cnt);

    // decode
    k_decode<<<cdiv(N_R, 4), 256, 0, stream>>>(r_agg, pooled, cnt, W_dec, b_dec, out, N_R);
}

// Round 7
// 776.182 us; speedup vs baseline: 11.0962x; 1.0634x over previous
//
#include <hip/hip_runtime.h>
#include <hip/hip_bf16.h>

#define HID 128
#define NEG_SLOPE 0.2f
#define CSPLIT 6
#define KNN_CB 64
#define NCAND (CSPLIT * 16)   // 96 candidates per collider

typedef _Float16 f16x8 __attribute__((ext_vector_type(8)));
typedef float f32x4 __attribute__((ext_vector_type(4)));

// ---------- helpers ----------
__device__ __forceinline__ bool cand_lt(float d1, int i1, float d2, int i2) {
    return d1 < d2 || (d1 == d2 && i1 < i2);
}
__device__ __forceinline__ void ins4(float s, int r, float bd[4], int bi[4]) {
    if (!cand_lt(s, r, bd[3], bi[3])) return;
    if (cand_lt(s, r, bd[0], bi[0])) {
        bd[3]=bd[2];bi[3]=bi[2]; bd[2]=bd[1];bi[2]=bi[1]; bd[1]=bd[0];bi[1]=bi[0]; bd[0]=s;bi[0]=r;
    } else if (cand_lt(s, r, bd[1], bi[1])) {
        bd[3]=bd[2];bi[3]=bi[2]; bd[2]=bd[1];bi[2]=bi[1]; bd[1]=s;bi[1]=r;
    } else if (cand_lt(s, r, bd[2], bi[2])) {
        bd[3]=bd[2];bi[3]=bi[2]; bd[2]=s;bi[2]=r;
    } else {
        bd[3]=s;bi[3]=r;
    }
}
__device__ __forceinline__ void ins3(float s, int r, float fd[3], int fi[3]) {
    if (!cand_lt(s, r, fd[2], fi[2])) return;
    if (cand_lt(s, r, fd[0], fi[0])) {
        fd[2]=fd[1];fi[2]=fi[1]; fd[1]=fd[0];fi[1]=fi[0]; fd[0]=s;fi[0]=r;
    } else if (cand_lt(s, r, fd[1], fi[1])) {
        fd[2]=fd[1];fi[2]=fi[1]; fd[1]=s;fi[1]=r;
    } else {
        fd[2]=s;fi[2]=r;
    }
}

// ---------- CSR build ----------
__global__ void k_deg(const int* __restrict__ ei, int E, int n, int* __restrict__ deg) {
    int i = blockIdx.x * blockDim.x + threadIdx.x;
    if (i >= E + n) return;
    int d = (i < E) ? ei[E + i] : i - E;
    atomicAdd(&deg[d], 1);
}

__global__ void k_scan(const int* __restrict__ deg, int* __restrict__ off,
                       int* __restrict__ cursor, int n) {
    __shared__ int carry;
    __shared__ int buf[256];
    int t = threadIdx.x;
    if (t == 0) carry = 0;
    __syncthreads();
    for (int base = 0; base < n; base += 256) {
        int i = base + t;
        int v = (i < n) ? deg[i] : 0;
        buf[t] = v;
        __syncthreads();
        for (int o = 1; o < 256; o <<= 1) {
            int add = (t >= o) ? buf[t - o] : 0;
            __syncthreads();
            buf[t] += add;
            __syncthreads();
        }
        int excl = carry + buf[t] - v;
        if (i < n) { off[i] = excl; cursor[i] = excl; }
        __syncthreads();
        if (t == 255) carry += buf[255];
        __syncthreads();
    }
    if (t == 0) off[n] = carry;
}

__global__ void k_scatter(const int* __restrict__ ei, int E, int n,
                          int* __restrict__ cursor, int* __restrict__ csr) {
    int i = blockIdx.x * blockDim.x + threadIdx.x;
    if (i >= E + n) return;
    int s, d;
    if (i < E) { s = ei[i]; d = ei[E + i]; } else { s = d = i - E; }
    int pos = atomicAdd(&cursor[d], 1);
    csr[pos] = s;
}

// ---------- linear: 4 nodes per block (128 thr), W reads shared ----------
__global__ __launch_bounds__(128) void k_linear(
    const float* __restrict__ x, const float* __restrict__ W,
    const float* __restrict__ a_src, const float* __restrict__ a_dst,
    float* __restrict__ h, float* __restrict__ es, float* __restrict__ ed,
    int d_in, int n) {
    int n0 = blockIdx.x * 4;
    int t = threadIdx.x;
    int w = t >> 6, lane = t & 63;
    __shared__ float xs[4][HID];
    __shared__ float p1[2], p2[2];
#pragma unroll
    for (int u = 0; u < 4; ++u) {
        int node = n0 + u;
        if (t < d_in) xs[u][t] = (node < n) ? x[(size_t)node * d_in + t] : 0.f;
    }
    __syncthreads();
    float acc[4] = {0.f, 0.f, 0.f, 0.f};
    for (int k = 0; k < d_in; ++k) {
        float wv = W[k * HID + t];
#pragma unroll
        for (int u = 0; u < 4; ++u) acc[u] += xs[u][k] * wv;
    }
    float asv = a_src[t], adv = a_dst[t];
    for (int u = 0; u < 4; ++u) {
        int node = n0 + u;
        if (node >= n) break;                     // uniform across block
        h[(size_t)node * HID + t] = acc[u];
        float v1 = acc[u] * asv, v2 = acc[u] * adv;
#pragma unroll
        for (int o = 32; o > 0; o >>= 1) { v1 += __shfl_xor(v1, o); v2 += __shfl_xor(v2, o); }
        if (lane == 0) { p1[w] = v1; p2[w] = v2; }
        __syncthreads();
        if (t == 0) { es[node] = p1[0] + p1[1]; ed[node] = p2[0] + p2[1]; }
        __syncthreads();
    }
}

// ---------- fused GAT aggregation over CSR (wave per dst node) ----------
__global__ __launch_bounds__(256) void k_gat_csr(
    const int* __restrict__ off, const int* __restrict__ csr,
    const float* __restrict__ es, const float* __restrict__ ed,
    const float* __restrict__ h, const float* __restrict__ b,
    float* __restrict__ agg, int n) {
    int node = blockIdx.x * 4 + (threadIdx.x >> 6);
    int lane = threadIdx.x & 63;
    if (node >= n) return;                        // wave-uniform
    int beg = off[node], end = off[node + 1];
    float edd = ed[node];
    // pass 1: segment max (lane-parallel)
    float m = -INFINITY;
    for (int j = beg + lane; j < end; j += 64) {
        int s = csr[j];
        float e = es[s] + edd;
        e = e > 0.f ? e : NEG_SLOPE * e;
        m = fmaxf(m, e);
    }
#pragma unroll
    for (int o = 32; o > 0; o >>= 1) m = fmaxf(m, __shfl_xor(m, o));
    // pass 2: 2-way unrolled accumulate (independent FMA chains, 4 loads/iter)
    float den = 0.f, a0 = 0.f, a1 = 0.f;
    int j = beg;
    for (; j + 1 < end; j += 2) {
        int s0 = csr[j], s1 = csr[j + 1];
        float e0 = es[s0] + edd;
        float e1 = es[s1] + edd;
        e0 = e0 > 0.f ? e0 : NEG_SLOPE * e0;
        e1 = e1 > 0.f ? e1 : NEG_SLOPE * e1;
        float ex0 = expf(e0 - m);
        float ex1 = expf(e1 - m);
        float h00 = h[(size_t)s0 * HID + lane];
        float h01 = h[(size_t)s0 * HID + 64 + lane];
        float h10 = h[(size_t)s1 * HID + lane];
        float h11 = h[(size_t)s1 * HID + 64 + lane];
        den += ex0 + ex1;
        a0 += ex0 * h00 + ex1 * h10;
        a1 += ex0 * h01 + ex1 * h11;
    }
    if (j < end) {
        int s0 = csr[j];
        float e0 = es[s0] + edd;
        e0 = e0 > 0.f ? e0 : NEG_SLOPE * e0;
        float ex0 = expf(e0 - m);
        den += ex0;
        a0 += ex0 * h[(size_t)s0 * HID + lane];
        a1 += ex0 * h[(size_t)s0 * HID + 64 + lane];
    }
    float inv = 1.f / fmaxf(den, 1e-16f);
    float v0 = a0 * inv + b[lane];
    float v1 = a1 * inv + b[64 + lane];
    agg[(size_t)node * HID + lane] = v0 > 0.f ? v0 : 0.f;
    agg[(size_t)node * HID + 64 + lane] = v1 > 0.f ? v1 : 0.f;
}

// norm (optional) + fp32 -> f16 split
__global__ void k_norm_split(const float* __restrict__ h, float* __restrict__ n2,
                             _Float16* __restrict__ h2, int do_norm) {
    int node = blockIdx.x;
    int t = threadIdx.x;
    float v = h[(long long)node * HID + t];
    h2[(long long)node * HID + t] = (_Float16)v;
    if (do_norm) {
        __shared__ float s[HID];
        s[t] = v * v;
        __syncthreads();
        for (int off = 64; off > 0; off >>= 1) {
            if (t < off) s[t] += s[t + off];
            __syncthreads();
        }
        if (t == 0) n2[node] = s[0];
    }
}

// ---------- MFMA KNN scan (unchanged) ----------
__global__ __launch_bounds__(256) void k_knn_scan(
    const _Float16* __restrict__ hr2, const _Float16* __restrict__ hc2,
    const float* __restrict__ nr2, int n_c, int n_r, int rs_chunk,
    int* __restrict__ cand_i) {
    __shared__ _Float16 lds[2][64 * HID];
    int t = threadIdx.x, w = t >> 6, lane = t & 63;
    int li = lane & 15, q = lane >> 4;
    int c0 = blockIdx.x * KNN_CB;
    int split = blockIdx.y;
    int rbeg = split * rs_chunk;
    int rows = min(rs_chunk, n_r - rbeg);
    int rend = rbeg + rows;

    if (rows <= 0) {
        int c = c0 + w * 16 + li;
        if (c < n_c) {
            size_t base = ((size_t)(c * CSPLIT + split) * 4 + q) * 4;
            for (int k = 0; k < 4; ++k) cand_i[base + k] = 0x7fffffff;
        }
        return;
    }

    // B fragments: collider col = li, k = ks*32 + q*8 .. +7
    f16x8 bf[4];
    {
        int c = c0 + w * 16 + li;
        int cc = min(c, n_c - 1);
#pragma unroll
        for (int ks = 0; ks < 4; ++ks)
            bf[ks] = *(const f16x8*)(hc2 + (size_t)cc * HID + ks * 32 + q * 8);
    }

    float bd[4]; int bi[4];
#pragma unroll
    for (int k = 0; k < 4; ++k) { bd[k] = INFINITY; bi[k] = 0x7fffffff; }

    int nch = (rows + 63) >> 6;

    auto STAGE = [&](int bsel, int R) {
#pragma unroll
        for (int j = 0; j < 4; ++j) {
            int row = w * 16 + j * 4 + q;
            int gr = min(R + row, n_r - 1);
            int sslot = li ^ (row & 7);
            const _Float16* src = hr2 + (size_t)gr * HID + sslot * 8;
            _Float16* dst = &lds[bsel][(w * 16 + j * 4) * HID];  // wave-uniform
            __builtin_amdgcn_global_load_lds(
                (const __attribute__((address_space(1))) void*)src,
                (__attribute__((address_space(3))) void*)dst, 16, 0, 0);
        }
    };

    STAGE(0, rbeg);
    __syncthreads();

    for (int ch = 0; ch < nch; ++ch) {
        int cur = ch & 1;
        if (ch + 1 < nch) STAGE(cur ^ 1, rbeg + (ch + 1) * 64);  // prefetch
        int R = rbeg + ch * 64;
        int rows_rem = rend - R;
        const _Float16* buf = lds[cur];
#pragma unroll
        for (int tt = 0; tt < 4; ++tt) {
            int br = tt * 16;
            if (br < rows_rem) {
                f32x4 a0 = {0.f, 0.f, 0.f, 0.f};
                int lr = br + li;
                int sw = lr & 7;
#pragma unroll
                for (int ks = 0; ks < 4; ++ks) {
                    f16x8 af = *(const f16x8*)(&buf[lr * HID + (((ks * 4 + q) ^ sw) << 3)]);
                    a0 = __builtin_amdgcn_mfma_f32_16x16x32_f16(af, bf[ks], a0, 0, 0, 0);
                }
                int r_base = R + br + q * 4;
                float4 nrv = *(const float4*)(nr2 + r_base);
                float sv[4] = {nrv.x, nrv.y, nrv.z, nrv.w};
#pragma unroll
                for (int i = 0; i < 4; ++i) {
                    int r = r_base + i;
                    if (r < rend) ins4(sv[i] - 2.f * a0[i], r, bd, bi);
                }
            }
        }
        __syncthreads();
    }

    {
        int c = c0 + w * 16 + li;
        if (c < n_c) {
            size_t base = ((size_t)(c * CSPLIT + split) * 4 + q) * 4;
#pragma unroll
            for (int k = 0; k < 4; ++k) cand_i[base + k] = bi[k];
        }
    }
}

// ---------- exact rerank + pooling: block per collider, coalesced gathers ----
// 96 cands x 32 float4 = 3072 items; thread t owns (j = p*8 + t/32, k4 = t%32)
// for p = 0..11. Each 32-lane group reads one candidate row CONTIGUOUSLY
// (512 B burst); all 12 row-loads issued as an independent batch (high MLP);
// 5-stage segmented butterfly per group; top-3 merge identical (d, idx)
// tie-break as previous rounds.
__global__ __launch_bounds__(256) void k_rerank(
    const int* __restrict__ cand_i, const float* __restrict__ hc,
    const float* __restrict__ hr, const float* __restrict__ nr2,
    int n_r, float* __restrict__ pooled, float* __restrict__ cnt) {
    int c = blockIdx.x;
    int t = threadIdx.x;
    __shared__ float hcs[HID];
    __shared__ int ci[NCAND];
    __shared__ float sc[NCAND];
    __shared__ int scr[NCAND];
    __shared__ int bidx[3];
    if (t < HID) hcs[t] = hc[(size_t)c * HID + t];
    if (t < NCAND) {
        int r = cand_i[(size_t)c * NCAND + t];
        ci[t] = ((unsigned)r < (unsigned)n_r) ? r : -1;
    }
    __syncthreads();

    int k4 = t & 31;
    int g = t >> 5;                                // 0..7
    const float4* hr4 = (const float4*)hr;
    float4 a = ((const float4*)hcs)[k4];

    int rj[12];
    float4 v[12];
#pragma unroll
    for (int p = 0; p < 12; ++p) {                 // issue all loads (MLP)
        rj[p] = ci[p * 8 + g];
        v[p] = hr4[(size_t)max(rj[p], 0) * 32 + k4];
    }
    float fd[3] = {INFINITY, INFINITY, INFINITY};
    int fi[3] = {0x7fffffff, 0x7fffffff, 0x7fffffff};
#pragma unroll
    for (int p = 0; p < 12; ++p) {
        float d = a.x * v[p].x + a.y * v[p].y + a.z * v[p].z + a.w * v[p].w;
#pragma unroll
        for (int o = 1; o < 32; o <<= 1) d += __shfl_xor(d, o);
        if (k4 == 0) {
            int j = p * 8 + g;
            sc[j] = (rj[p] >= 0) ? nr2[rj[p]] - 2.f * d : INFINITY;
            scr[j] = (rj[p] >= 0) ? rj[p] : 0x7fffffff;
        }
    }
    __syncthreads();
    if (t < 64) {
        ins3(sc[t], scr[t], fd, fi);
        if (t < 32) ins3(sc[64 + t], scr[64 + t], fd, fi);
#pragma unroll
        for (int o = 1; o < 64; o <<= 1) {
            float sd0 = __shfl_xor(fd[0], o), sd1 = __shfl_xor(fd[1], o), sd2 = __shfl_xor(fd[2], o);
            int si0 = __shfl_xor(fi[0], o), si1 = __shfl_xor(fi[1], o), si2 = __shfl_xor(fi[2], o);
            ins3(sd0, si0, fd, fi);
            ins3(sd1, si1, fd, fi);
            ins3(sd2, si2, fd, fi);
        }
        if (t == 0) { bidx[0] = fi[0]; bidx[1] = fi[1]; bidx[2] = fi[2]; }
    }
    __syncthreads();
    if (t < HID) {
        float hv = hcs[t];
#pragma unroll
        for (int q = 0; q < 3; ++q) {
            int b = bidx[q];
            if (b >= 0 && b < n_r) {
                atomicAdd(&pooled[(size_t)b * HID + t], hv);
                if (t == 0) atomicAdd(&cnt[b], 1.0f);
            }
        }
    }
}

// one wave per resting node
__global__ void k_decode(const float* __restrict__ hr, const float* __restrict__ pooled,
                         const float* __restrict__ cnt, const float* __restrict__ Wd,
                         const float* __restrict__ bd, float* __restrict__ out, int n) {
    int node = blockIdx.x * (blockDim.x / 64) + (threadIdx.x >> 6);
    int lane = threadIdx.x & 63;
    if (node >= n) return;
    float c = fmaxf(cnt[node], 1.0f);
    float a0 = 0.f, a1 = 0.f, a2 = 0.f;
    for (int k = lane; k < HID; k += 64) {
        float v = hr[(long long)node * HID + k];
        a0 += v * Wd[k * 3 + 0];
        a1 += v * Wd[k * 3 + 1];
        a2 += v * Wd[k * 3 + 2];
        float p = pooled[(long long)node * HID + k] / c;
        a0 += p * Wd[(HID + k) * 3 + 0];
        a1 += p * Wd[(HID + k) * 3 + 1];
        a2 += p * Wd[(HID + k) * 3 + 2];
    }
    for (int off = 32; off > 0; off >>= 1) {
        a0 += __shfl_down(a0, off);
        a1 += __shfl_down(a1, off);
        a2 += __shfl_down(a2, off);
    }
    if (lane == 0) {
        out[(long long)node * 3 + 0] = a0 + bd[0];
        out[(long long)node * 3 + 1] = a1 + bd[1];
        out[(long long)node * 3 + 2] = a2 + bd[2];
    }
}

// ---------- launch ----------
static inline int cdiv(long long a, int b) { return (int)((a + b - 1) / b); }

extern "C" void kernel_launch(void* const* d_in, const int* in_sizes, int n_in,
                              void* d_out, int out_size, void* d_ws, size_t ws_size,
                              hipStream_t stream) {
    const float* x_r = (const float*)d_in[0];
    const float* x_c = (const float*)d_in[1];
    const int* ei_r = (const int*)d_in[2];
    const int* ei_c = (const int*)d_in[3];
    const float* W_r1 = (const float*)d_in[5];
    const float* as_r1 = (const float*)d_in[6];
    const float* ad_r1 = (const float*)d_in[7];
    const float* b_r1 = (const float*)d_in[8];
    const float* W_r2 = (const float*)d_in[9];
    const float* as_r2 = (const float*)d_in[10];
    const float* ad_r2 = (const float*)d_in[11];
    const float* b_r2 = (const float*)d_in[12];
    const float* W_c1 = (const float*)d_in[13];
    const float* as_c1 = (const float*)d_in[14];
    const float* ad_c1 = (const float*)d_in[15];
    const float* b_c1 = (const float*)d_in[16];
    const float* W_c2 = (const float*)d_in[17];
    const float* as_c2 = (const float*)d_in[18];
    const float* ad_c2 = (const float*)d_in[19];
    const float* b_c2 = (const float*)d_in[20];
    const float* W_dec = (const float*)d_in[21];
    const float* b_dec = (const float*)d_in[22];
    float* out = (float*)d_out;

    const int N_R = in_sizes[0] / 6;
    const int N_C = in_sizes[1] / 6;
    const int E_R = in_sizes[2] / 2;
    const int E_C = in_sizes[3] / 2;

    float* ws = (float*)d_ws;
    size_t off = 0;
    auto alloc = [&](size_t nf) {
        float* p = ws + off;
        off += (nf + 3) & ~(size_t)3;
        return p;
    };
    float* r_h    = alloc((size_t)N_R * HID);
    float* r_agg  = alloc((size_t)N_R * HID);
    float* c_h    = alloc((size_t)N_C * HID);
    float* c_agg  = alloc((size_t)N_C * HID);
    float* pooled = alloc((size_t)N_R * HID);
    float* r_es = alloc(N_R);
    float* r_ed = alloc(N_R);
    float* c_es = alloc(N_C);
    float* c_ed = alloc(N_C);
    float* cnt = alloc(N_R);
    float* nr2 = alloc((size_t)N_R + 64);
    _Float16* hr2 = (_Float16*)alloc((size_t)N_R * HID / 2);
    _Float16* hc2 = (_Float16*)alloc((size_t)N_C * HID / 2);
    int* cand_i = (int*)alloc((size_t)N_C * NCAND);
    // CSR (resting)
    int* r_deg = (int*)alloc(N_R);
    int* r_off = (int*)alloc((size_t)N_R + 1);
    int* r_cur = (int*)alloc(N_R);
    int* r_csr = (int*)alloc((size_t)E_R + N_R);
    // CSR (collider)
    int* c_deg = (int*)alloc(N_C);
    int* c_off = (int*)alloc((size_t)N_C + 1);
    int* c_cur = (int*)alloc(N_C);
    int* c_csr = (int*)alloc((size_t)E_C + N_C);
    (void)ws_size; (void)n_in; (void)out_size;

    auto build_csr = [&](const int* ei, int E, int n, int* deg, int* offp, int* cur, int* csr) {
        hipMemsetAsync(deg, 0, (size_t)n * sizeof(int), stream);
        k_deg<<<cdiv(E + n, 256), 256, 0, stream>>>(ei, E, n, deg);
        k_scan<<<1, 256, 0, stream>>>(deg, offp, cur, n);
        k_scatter<<<cdiv(E + n, 256), 256, 0, stream>>>(ei, E, n, cur, csr);
    };
    auto gat = [&](const float* x, int d_in_dim, int n, const int* offp, const int* csr,
                   const float* W, const float* as_, const float* ad_, const float* b,
                   float* h, float* es, float* ed, float* agg) {
        k_linear<<<cdiv(n, 4), 128, 0, stream>>>(x, W, as_, ad_, h, es, ed, d_in_dim, n);
        k_gat_csr<<<cdiv(n, 4), 256, 0, stream>>>(offp, csr, es, ed, h, b, agg, n);
    };

    // resting branch
    build_csr(ei_r, E_R, N_R, r_deg, r_off, r_cur, r_csr);
    gat(x_r, 6, N_R, r_off, r_csr, W_r1, as_r1, ad_r1, b_r1, r_h, r_es, r_ed, r_agg);
    gat(r_agg, HID, N_R, r_off, r_csr, W_r2, as_r2, ad_r2, b_r2, r_h, r_es, r_ed, r_agg);
    // collider branch
    build_csr(ei_c, E_C, N_C, c_deg, c_off, c_cur, c_csr);
    gat(x_c, 6, N_C, c_off, c_csr, W_c1, as_c1, ad_c1, b_c1, c_h, c_es, c_ed, c_agg);
    gat(c_agg, HID, N_C, c_off, c_csr, W_c2, as_c2, ad_c2, b_c2, c_h, c_es, c_ed, c_agg);

    // KNN: f16 convert + norms
    hipMemsetAsync(pooled, 0, (size_t)N_R * HID * sizeof(float), stream);
    hipMemsetAsync(cnt, 0, (size_t)N_R * sizeof(float), stream);
    k_norm_split<<<N_R, HID, 0, stream>>>(r_agg, nr2, hr2, 1);
    k_norm_split<<<N_C, HID, 0, stream>>>(c_agg, nr2, hc2, 0);

    // MFMA candidate scan
    int RS = cdiv(N_R, CSPLIT * 64) * 64;
    dim3 sgrid(cdiv(N_C, KNN_CB), CSPLIT);
    k_knn_scan<<<sgrid, 256, 0, stream>>>(hr2, hc2, nr2, N_C, N_R, RS, cand_i);

    // exact rerank + pooling (block per collider, coalesced)
    k_rerank<<<N_C, 256, 0, stream>>>(cand_i, c_agg, r_agg, nr2, N_R, pooled, cnt);

    // decode
    k_decode<<<cdiv(N_R, 4), 256, 0, stream>>>(r_agg, pooled, cnt, W_dec, b_dec, out, N_R);
}

// Round 8
// 711.931 us; speedup vs baseline: 12.0977x; 1.0902x over previous
//
#include <hip/hip_runtime.h>
#include <hip/hip_bf16.h>

#define HID 128
#define NEG_SLOPE 0.2f
#define CSPLIT 4
#define KNN_CB 64
#define NCAND (CSPLIT * 16)   // 64 candidates per collider

typedef _Float16 f16x8 __attribute__((ext_vector_type(8)));
typedef float f32x4 __attribute__((ext_vector_type(4)));

// ---------- helpers ----------
__device__ __forceinline__ bool cand_lt(float d1, int i1, float d2, int i2) {
    return d1 < d2 || (d1 == d2 && i1 < i2);
}
__device__ __forceinline__ void ins4(float s, int r, float bd[4], int bi[4]) {
    if (!cand_lt(s, r, bd[3], bi[3])) return;
    if (cand_lt(s, r, bd[0], bi[0])) {
        bd[3]=bd[2];bi[3]=bi[2]; bd[2]=bd[1];bi[2]=bi[1]; bd[1]=bd[0];bi[1]=bi[0]; bd[0]=s;bi[0]=r;
    } else if (cand_lt(s, r, bd[1], bi[1])) {
        bd[3]=bd[2];bi[3]=bi[2]; bd[2]=bd[1];bi[2]=bi[1]; bd[1]=s;bi[1]=r;
    } else if (cand_lt(s, r, bd[2], bi[2])) {
        bd[3]=bd[2];bi[3]=bi[2]; bd[2]=s;bi[2]=r;
    } else {
        bd[3]=s;bi[3]=r;
    }
}
__device__ __forceinline__ void ins3(float s, int r, float fd[3], int fi[3]) {
    if (!cand_lt(s, r, fd[2], fi[2])) return;
    if (cand_lt(s, r, fd[0], fi[0])) {
        fd[2]=fd[1];fi[2]=fi[1]; fd[1]=fd[0];fi[1]=fi[0]; fd[0]=s;fi[0]=r;
    } else if (cand_lt(s, r, fd[1], fi[1])) {
        fd[2]=fd[1];fi[2]=fi[1]; fd[1]=s;fi[1]=r;
    } else {
        fd[2]=s;fi[2]=r;
    }
}

// ---------- CSR build ----------
__global__ void k_deg(const int* __restrict__ ei, int E, int n, int* __restrict__ deg) {
    int i = blockIdx.x * blockDim.x + threadIdx.x;
    if (i >= E + n) return;
    int d = (i < E) ? ei[E + i] : i - E;
    atomicAdd(&deg[d], 1);
}

// per-256-chunk sums
__global__ void k_chunksum(const int* __restrict__ deg, int* __restrict__ bsum, int n) {
    int t = threadIdx.x;
    int i = blockIdx.x * 256 + t;
    int v = (i < n) ? deg[i] : 0;
#pragma unroll
    for (int o = 1; o < 64; o <<= 1) v += __shfl_xor(v, o);
    __shared__ int wsum[4];
    if ((t & 63) == 0) wsum[t >> 6] = v;
    __syncthreads();
    if (t == 0) bsum[blockIdx.x] = wsum[0] + wsum[1] + wsum[2] + wsum[3];
}

// exclusive scan of nb (<=256) chunk sums, in place; a[nb] = total
__global__ void k_scan_small(int* __restrict__ a, int nb) {
    __shared__ int buf[256];
    int t = threadIdx.x;
    int v = (t < nb) ? a[t] : 0;
    buf[t] = v;
    __syncthreads();
    for (int o = 1; o < 256; o <<= 1) {
        int add = (t >= o) ? buf[t - o] : 0;
        __syncthreads();
        buf[t] += add;
        __syncthreads();
    }
    if (t < nb) a[t] = buf[t] - v;
    if (t == 0) a[nb] = buf[nb - 1];
}

// per-chunk re-scan + base offset -> off / cursor; off[n] = total
__global__ void k_scan_apply(const int* __restrict__ deg, const int* __restrict__ bsum,
                             int* __restrict__ off, int* __restrict__ cur, int n) {
    __shared__ int buf[256];
    int b = blockIdx.x, t = threadIdx.x;
    int i = b * 256 + t;
    int v = (i < n) ? deg[i] : 0;
    buf[t] = v;
    __syncthreads();
    for (int o = 1; o < 256; o <<= 1) {
        int add = (t >= o) ? buf[t - o] : 0;
        __syncthreads();
        buf[t] += add;
        __syncthreads();
    }
    int excl = bsum[b] + buf[t] - v;
    if (i < n) { off[i] = excl; cur[i] = excl; }
    if (b == 0 && t == 0) off[n] = bsum[gridDim.x];
}

__global__ void k_scatter(const int* __restrict__ ei, int E, int n,
                          int* __restrict__ cursor, int* __restrict__ csr) {
    int i = blockIdx.x * blockDim.x + threadIdx.x;
    if (i >= E + n) return;
    int s, d;
    if (i < E) { s = ei[i]; d = ei[E + i]; } else { s = d = i - E; }
    int pos = atomicAdd(&cursor[d], 1);
    csr[pos] = s;
}

// ---------- linear: 4 nodes per block (128 thr), W reads shared ----------
__global__ __launch_bounds__(128) void k_linear(
    const float* __restrict__ x, const float* __restrict__ W,
    const float* __restrict__ a_src, const float* __restrict__ a_dst,
    float* __restrict__ h, float* __restrict__ es, float* __restrict__ ed,
    int d_in, int n) {
    int n0 = blockIdx.x * 4;
    int t = threadIdx.x;
    int w = t >> 6, lane = t & 63;
    __shared__ float xs[4][HID];
    __shared__ float p1[2], p2[2];
#pragma unroll
    for (int u = 0; u < 4; ++u) {
        int node = n0 + u;
        if (t < d_in) xs[u][t] = (node < n) ? x[(size_t)node * d_in + t] : 0.f;
    }
    __syncthreads();
    float acc[4] = {0.f, 0.f, 0.f, 0.f};
    for (int k = 0; k < d_in; ++k) {
        float wv = W[k * HID + t];
#pragma unroll
        for (int u = 0; u < 4; ++u) acc[u] += xs[u][k] * wv;
    }
    float asv = a_src[t], adv = a_dst[t];
    for (int u = 0; u < 4; ++u) {
        int node = n0 + u;
        if (node >= n) break;                     // uniform across block
        h[(size_t)node * HID + t] = acc[u];
        float v1 = acc[u] * asv, v2 = acc[u] * adv;
#pragma unroll
        for (int o = 32; o > 0; o >>= 1) { v1 += __shfl_xor(v1, o); v2 += __shfl_xor(v2, o); }
        if (lane == 0) { p1[w] = v1; p2[w] = v2; }
        __syncthreads();
        if (t == 0) { es[node] = p1[0] + p1[1]; ed[node] = p2[0] + p2[1]; }
        __syncthreads();
    }
}

// ---------- fused GAT aggregation over CSR (wave per dst node) ----------
// optional epilogue: f16 copy of output row (h16) and squared-norm (n2)
__global__ __launch_bounds__(256) void k_gat_csr(
    const int* __restrict__ off, const int* __restrict__ csr,
    const float* __restrict__ es, const float* __restrict__ ed,
    const float* __restrict__ h, const float* __restrict__ b,
    float* __restrict__ agg, int n,
    _Float16* __restrict__ h16, float* __restrict__ n2) {
    int node = blockIdx.x * 4 + (threadIdx.x >> 6);
    int lane = threadIdx.x & 63;
    if (node >= n) return;                        // wave-uniform
    int beg = off[node], end = off[node + 1];
    float edd = ed[node];
    // pass 1: segment max (lane-parallel)
    float m = -INFINITY;
    for (int j = beg + lane; j < end; j += 64) {
        int s = csr[j];
        float e = es[s] + edd;
        e = e > 0.f ? e : NEG_SLOPE * e;
        m = fmaxf(m, e);
    }
#pragma unroll
    for (int o = 32; o > 0; o >>= 1) m = fmaxf(m, __shfl_xor(m, o));
    // pass 2: 2-way unrolled accumulate
    float den = 0.f, a0 = 0.f, a1 = 0.f;
    int j = beg;
    for (; j + 1 < end; j += 2) {
        int s0 = csr[j], s1 = csr[j + 1];
        float e0 = es[s0] + edd;
        float e1 = es[s1] + edd;
        e0 = e0 > 0.f ? e0 : NEG_SLOPE * e0;
        e1 = e1 > 0.f ? e1 : NEG_SLOPE * e1;
        float ex0 = expf(e0 - m);
        float ex1 = expf(e1 - m);
        float h00 = h[(size_t)s0 * HID + lane];
        float h01 = h[(size_t)s0 * HID + 64 + lane];
        float h10 = h[(size_t)s1 * HID + lane];
        float h11 = h[(size_t)s1 * HID + 64 + lane];
        den += ex0 + ex1;
        a0 += ex0 * h00 + ex1 * h10;
        a1 += ex0 * h01 + ex1 * h11;
    }
    if (j < end) {
        int s0 = csr[j];
        float e0 = es[s0] + edd;
        e0 = e0 > 0.f ? e0 : NEG_SLOPE * e0;
        float ex0 = expf(e0 - m);
        den += ex0;
        a0 += ex0 * h[(size_t)s0 * HID + lane];
        a1 += ex0 * h[(size_t)s0 * HID + 64 + lane];
    }
    float inv = 1.f / fmaxf(den, 1e-16f);
    float v0 = a0 * inv + b[lane];
    float v1 = a1 * inv + b[64 + lane];
    float r0 = v0 > 0.f ? v0 : 0.f;
    float r1 = v1 > 0.f ? v1 : 0.f;
    agg[(size_t)node * HID + lane] = r0;
    agg[(size_t)node * HID + 64 + lane] = r1;
    if (h16) {
        h16[(size_t)node * HID + lane] = (_Float16)r0;
        h16[(size_t)node * HID + 64 + lane] = (_Float16)r1;
    }
    if (n2) {
        float s2 = r0 * r0 + r1 * r1;
#pragma unroll
        for (int o = 32; o > 0; o >>= 1) s2 += __shfl_xor(s2, o);
        if (lane == 0) n2[node] = s2;
    }
}

// ---------- MFMA KNN scan (structure unchanged; CSPLIT now 4) ----------
__global__ __launch_bounds__(256) void k_knn_scan(
    const _Float16* __restrict__ hr2, const _Float16* __restrict__ hc2,
    const float* __restrict__ nr2, int n_c, int n_r, int rs_chunk,
    int* __restrict__ cand_i) {
    __shared__ _Float16 lds[2][64 * HID];
    int t = threadIdx.x, w = t >> 6, lane = t & 63;
    int li = lane & 15, q = lane >> 4;
    int c0 = blockIdx.x * KNN_CB;
    int split = blockIdx.y;
    int rbeg = split * rs_chunk;
    int rows = min(rs_chunk, n_r - rbeg);
    int rend = rbeg + rows;

    if (rows <= 0) {
        int c = c0 + w * 16 + li;
        if (c < n_c) {
            size_t base = ((size_t)(c * CSPLIT + split) * 4 + q) * 4;
            for (int k = 0; k < 4; ++k) cand_i[base + k] = 0x7fffffff;
        }
        return;
    }

    // B fragments: collider col = li, k = ks*32 + q*8 .. +7
    f16x8 bf[4];
    {
        int c = c0 + w * 16 + li;
        int cc = min(c, n_c - 1);
#pragma unroll
        for (int ks = 0; ks < 4; ++ks)
            bf[ks] = *(const f16x8*)(hc2 + (size_t)cc * HID + ks * 32 + q * 8);
    }

    float bd[4]; int bi[4];
#pragma unroll
    for (int k = 0; k < 4; ++k) { bd[k] = INFINITY; bi[k] = 0x7fffffff; }

    int nch = (rows + 63) >> 6;

    auto STAGE = [&](int bsel, int R) {
#pragma unroll
        for (int j = 0; j < 4; ++j) {
            int row = w * 16 + j * 4 + q;
            int gr = min(R + row, n_r - 1);
            int sslot = li ^ (row & 7);
            const _Float16* src = hr2 + (size_t)gr * HID + sslot * 8;
            _Float16* dst = &lds[bsel][(w * 16 + j * 4) * HID];  // wave-uniform
            __builtin_amdgcn_global_load_lds(
                (const __attribute__((address_space(1))) void*)src,
                (__attribute__((address_space(3))) void*)dst, 16, 0, 0);
        }
    };

    STAGE(0, rbeg);
    __syncthreads();

    for (int ch = 0; ch < nch; ++ch) {
        int cur = ch & 1;
        if (ch + 1 < nch) STAGE(cur ^ 1, rbeg + (ch + 1) * 64);  // prefetch
        int R = rbeg + ch * 64;
        int rows_rem = rend - R;
        const _Float16* buf = lds[cur];
#pragma unroll
        for (int tt = 0; tt < 4; ++tt) {
            int br = tt * 16;
            if (br < rows_rem) {
                f32x4 a0 = {0.f, 0.f, 0.f, 0.f};
                int lr = br + li;
                int sw = lr & 7;
#pragma unroll
                for (int ks = 0; ks < 4; ++ks) {
                    f16x8 af = *(const f16x8*)(&buf[lr * HID + (((ks * 4 + q) ^ sw) << 3)]);
                    a0 = __builtin_amdgcn_mfma_f32_16x16x32_f16(af, bf[ks], a0, 0, 0, 0);
                }
                int r_base = R + br + q * 4;
                float4 nrv = *(const float4*)(nr2 + r_base);
                float sv[4] = {nrv.x, nrv.y, nrv.z, nrv.w};
#pragma unroll
                for (int i = 0; i < 4; ++i) {
                    int r = r_base + i;
                    if (r < rend) ins4(sv[i] - 2.f * a0[i], r, bd, bi);
                }
            }
        }
        __syncthreads();
    }

    {
        int c = c0 + w * 16 + li;
        if (c < n_c) {
            size_t base = ((size_t)(c * CSPLIT + split) * 4 + q) * 4;
#pragma unroll
            for (int k = 0; k < 4; ++k) cand_i[base + k] = bi[k];
        }
    }
}

// ---------- exact rerank + pooling: block per collider, coalesced, high MLP --
// 64 cands x 32 float4 = 2048 items; thread t owns (j = p*8 + t/32, k4 = t%32)
// for p = 0..7 — all 8 row-loads issued as an independent batch.
// __launch_bounds__(256,4) keeps <=128 VGPR so the batch stays in flight.
__global__ __launch_bounds__(256, 4) void k_rerank(
    const int* __restrict__ cand_i, const float* __restrict__ hc,
    const float* __restrict__ hr, const float* __restrict__ nr2,
    int n_r, float* __restrict__ pooled, float* __restrict__ cnt) {
    int c = blockIdx.x;
    int t = threadIdx.x;
    __shared__ float hcs[HID];
    __shared__ int ci[NCAND];
    __shared__ float sc[NCAND];
    __shared__ int scr[NCAND];
    __shared__ int bidx[3];
    if (t < HID) hcs[t] = hc[(size_t)c * HID + t];
    if (t < NCAND) {
        int r = cand_i[(size_t)c * NCAND + t];
        ci[t] = ((unsigned)r < (unsigned)n_r) ? r : -1;
    }
    __syncthreads();

    int k4 = t & 31;
    int g = t >> 5;                                // 0..7
    const float4* hr4 = (const float4*)hr;
    float4 a = ((const float4*)hcs)[k4];

    int rj[8];
    float4 v[8];
#pragma unroll
    for (int p = 0; p < 8; ++p) {                  // issue all loads (MLP)
        rj[p] = ci[p * 8 + g];
        v[p] = hr4[(size_t)max(rj[p], 0) * 32 + k4];
    }
    float fd[3] = {INFINITY, INFINITY, INFINITY};
    int fi[3] = {0x7fffffff, 0x7fffffff, 0x7fffffff};
#pragma unroll
    for (int p = 0; p < 8; ++p) {
        float d = a.x * v[p].x + a.y * v[p].y + a.z * v[p].z + a.w * v[p].w;
#pragma unroll
        for (int o = 1; o < 32; o <<= 1) d += __shfl_xor(d, o);
        if (k4 == 0) {
            int j = p * 8 + g;
            sc[j] = (rj[p] >= 0) ? nr2[rj[p]] - 2.f * d : INFINITY;
            scr[j] = (rj[p] >= 0) ? rj[p] : 0x7fffffff;
        }
    }
    __syncthreads();
    if (t < 64) {
        ins3(sc[t], scr[t], fd, fi);
#pragma unroll
        for (int o = 1; o < 64; o <<= 1) {
            float sd0 = __shfl_xor(fd[0], o), sd1 = __shfl_xor(fd[1], o), sd2 = __shfl_xor(fd[2], o);
            int si0 = __shfl_xor(fi[0], o), si1 = __shfl_xor(fi[1], o), si2 = __shfl_xor(fi[2], o);
            ins3(sd0, si0, fd, fi);
            ins3(sd1, si1, fd, fi);
            ins3(sd2, si2, fd, fi);
        }
        if (t == 0) { bidx[0] = fi[0]; bidx[1] = fi[1]; bidx[2] = fi[2]; }
    }
    __syncthreads();
    if (t < HID) {
        float hv = hcs[t];
#pragma unroll
        for (int q = 0; q < 3; ++q) {
            int b = bidx[q];
            if (b >= 0 && b < n_r) {
                atomicAdd(&pooled[(size_t)b * HID + t], hv);
                if (t == 0) atomicAdd(&cnt[b], 1.0f);
            }
        }
    }
}

// one wave per resting node
__global__ void k_decode(const float* __restrict__ hr, const float* __restrict__ pooled,
                         const float* __restrict__ cnt, const float* __restrict__ Wd,
                         const float* __restrict__ bd, float* __restrict__ out, int n) {
    int node = blockIdx.x * (blockDim.x / 64) + (threadIdx.x >> 6);
    int lane = threadIdx.x & 63;
    if (node >= n) return;
    float c = fmaxf(cnt[node], 1.0f);
    float a0 = 0.f, a1 = 0.f, a2 = 0.f;
    for (int k = lane; k < HID; k += 64) {
        float v = hr[(long long)node * HID + k];
        a0 += v * Wd[k * 3 + 0];
        a1 += v * Wd[k * 3 + 1];
        a2 += v * Wd[k * 3 + 2];
        float p = pooled[(long long)node * HID + k] / c;
        a0 += p * Wd[(HID + k) * 3 + 0];
        a1 += p * Wd[(HID + k) * 3 + 1];
        a2 += p * Wd[(HID + k) * 3 + 2];
    }
    for (int off = 32; off > 0; off >>= 1) {
        a0 += __shfl_down(a0, off);
        a1 += __shfl_down(a1, off);
        a2 += __shfl_down(a2, off);
    }
    if (lane == 0) {
        out[(long long)node * 3 + 0] = a0 + bd[0];
        out[(long long)node * 3 + 1] = a1 + bd[1];
        out[(long long)node * 3 + 2] = a2 + bd[2];
    }
}

// ---------- launch ----------
static inline int cdiv(long long a, int b) { return (int)((a + b - 1) / b); }

extern "C" void kernel_launch(void* const* d_in, const int* in_sizes, int n_in,
                              void* d_out, int out_size, void* d_ws, size_t ws_size,
                              hipStream_t stream) {
    const float* x_r = (const float*)d_in[0];
    const float* x_c = (const float*)d_in[1];
    const int* ei_r = (const int*)d_in[2];
    const int* ei_c = (const int*)d_in[3];
    const float* W_r1 = (const float*)d_in[5];
    const float* as_r1 = (const float*)d_in[6];
    const float* ad_r1 = (const float*)d_in[7];
    const float* b_r1 = (const float*)d_in[8];
    const float* W_r2 = (const float*)d_in[9];
    const float* as_r2 = (const float*)d_in[10];
    const float* ad_r2 = (const float*)d_in[11];
    const float* b_r2 = (const float*)d_in[12];
    const float* W_c1 = (const float*)d_in[13];
    const float* as_c1 = (const float*)d_in[14];
    const float* ad_c1 = (const float*)d_in[15];
    const float* b_c1 = (const float*)d_in[16];
    const float* W_c2 = (const float*)d_in[17];
    const float* as_c2 = (const float*)d_in[18];
    const float* ad_c2 = (const float*)d_in[19];
    const float* b_c2 = (const float*)d_in[20];
    const float* W_dec = (const float*)d_in[21];
    const float* b_dec = (const float*)d_in[22];
    float* out = (float*)d_out;

    const int N_R = in_sizes[0] / 6;
    const int N_C = in_sizes[1] / 6;
    const int E_R = in_sizes[2] / 2;
    const int E_C = in_sizes[3] / 2;

    float* ws = (float*)d_ws;
    size_t off = 0;
    auto alloc = [&](size_t nf) {
        float* p = ws + off;
        off += (nf + 3) & ~(size_t)3;
        return p;
    };
    float* r_h    = alloc((size_t)N_R * HID);
    float* r_agg  = alloc((size_t)N_R * HID);
    float* c_h    = alloc((size_t)N_C * HID);
    float* c_agg  = alloc((size_t)N_C * HID);
    float* pooled = alloc((size_t)N_R * HID);
    float* r_es = alloc(N_R);
    float* r_ed = alloc(N_R);
    float* c_es = alloc(N_C);
    float* c_ed = alloc(N_C);
    float* cnt = alloc(N_R);
    float* nr2 = alloc((size_t)N_R + 512);
    _Float16* hr2 = (_Float16*)alloc((size_t)N_R * HID / 2);
    _Float16* hc2 = (_Float16*)alloc((size_t)N_C * HID / 2);
    int* cand_i = (int*)alloc((size_t)N_C * NCAND);
    // CSR (resting)
    int* r_deg = (int*)alloc(N_R);
    int* r_off = (int*)alloc((size_t)N_R + 1);
    int* r_cur = (int*)alloc(N_R);
    int* r_csr = (int*)alloc((size_t)E_R + N_R);
    int* r_bsum = (int*)alloc(256);
    // CSR (collider)
    int* c_deg = (int*)alloc(N_C);
    int* c_off = (int*)alloc((size_t)N_C + 1);
    int* c_cur = (int*)alloc(N_C);
    int* c_csr = (int*)alloc((size_t)E_C + N_C);
    int* c_bsum = (int*)alloc(256);
    (void)ws_size; (void)n_in; (void)out_size;

    auto build_csr = [&](const int* ei, int E, int n, int* deg, int* offp, int* cur,
                         int* csr, int* bsum) {
        hipMemsetAsync(deg, 0, (size_t)n * sizeof(int), stream);
        k_deg<<<cdiv(E + n, 256), 256, 0, stream>>>(ei, E, n, deg);
        int nb = cdiv(n, 256);
        k_chunksum<<<nb, 256, 0, stream>>>(deg, bsum, n);
        k_scan_small<<<1, 256, 0, stream>>>(bsum, nb);
        k_scan_apply<<<nb, 256, 0, stream>>>(deg, bsum, offp, cur, n);
        k_scatter<<<cdiv(E + n, 256), 256, 0, stream>>>(ei, E, n, cur, csr);
    };
    auto gat = [&](const float* x, int d_in_dim, int n, const int* offp, const int* csr,
                   const float* W, const float* as_, const float* ad_, const float* b,
                   float* h, float* es, float* ed, float* agg,
                   _Float16* h16, float* n2) {
        k_linear<<<cdiv(n, 4), 128, 0, stream>>>(x, W, as_, ad_, h, es, ed, d_in_dim, n);
        k_gat_csr<<<cdiv(n, 4), 256, 0, stream>>>(offp, csr, es, ed, h, b, agg, n, h16, n2);
    };

    // resting branch
    build_csr(ei_r, E_R, N_R, r_deg, r_off, r_cur, r_csr, r_bsum);
    gat(x_r, 6, N_R, r_off, r_csr, W_r1, as_r1, ad_r1, b_r1, r_h, r_es, r_ed, r_agg,
        nullptr, nullptr);
    gat(r_agg, HID, N_R, r_off, r_csr, W_r2, as_r2, ad_r2, b_r2, r_h, r_es, r_ed, r_agg,
        hr2, nr2);
    // collider branch
    build_csr(ei_c, E_C, N_C, c_deg, c_off, c_cur, c_csr, c_bsum);
    gat(x_c, 6, N_C, c_off, c_csr, W_c1, as_c1, ad_c1, b_c1, c_h, c_es, c_ed, c_agg,
        nullptr, nullptr);
    gat(c_agg, HID, N_C, c_off, c_csr, W_c2, as_c2, ad_c2, b_c2, c_h, c_es, c_ed, c_agg,
        hc2, nullptr);

    // KNN pooling buffers
    hipMemsetAsync(pooled, 0, (size_t)N_R * HID * sizeof(float), stream);
    hipMemsetAsync(cnt, 0, (size_t)N_R * sizeof(float), stream);

    // MFMA candidate scan
    int RS = cdiv(N_R, CSPLIT * 64) * 64;
    dim3 sgrid(cdiv(N_C, KNN_CB), CSPLIT);
    k_knn_scan<<<sgrid, 256, 0, stream>>>(hr2, hc2, nr2, N_C, N_R, RS, cand_i);

    // exact rerank + pooling (block per collider, coalesced, high MLP)
    k_rerank<<<N_C, 256, 0, stream>>>(cand_i, c_agg, r_agg, nr2, N_R, pooled, cnt);

    // decode
    k_decode<<<cdiv(N_R, 4), 256, 0, stream>>>(r_agg, pooled, cnt, W_dec, b_dec, out, N_R);
}

// Round 9
// 619.397 us; speedup vs baseline: 13.9050x; 1.1494x over previous
//
#include <hip/hip_runtime.h>
#include <hip/hip_bf16.h>

#define HID 128
#define NEG_SLOPE 0.2f
#define CSPLIT 8
#define KNN_CB 64
#define NCAND (CSPLIT * 12)   // 96 candidates per collider (3 per row-class per split)

typedef _Float16 f16x8 __attribute__((ext_vector_type(8)));
typedef float f32x4 __attribute__((ext_vector_type(4)));

// ---------- helpers ----------
__device__ __forceinline__ bool cand_lt(float d1, int i1, float d2, int i2) {
    return d1 < d2 || (d1 == d2 && i1 < i2);
}
__device__ __forceinline__ void ins3(float s, int r, float fd[3], int fi[3]) {
    if (!cand_lt(s, r, fd[2], fi[2])) return;
    if (cand_lt(s, r, fd[0], fi[0])) {
        fd[2]=fd[1];fi[2]=fi[1]; fd[1]=fd[0];fi[1]=fi[0]; fd[0]=s;fi[0]=r;
    } else if (cand_lt(s, r, fd[1], fi[1])) {
        fd[2]=fd[1];fi[2]=fi[1]; fd[1]=s;fi[1]=r;
    } else {
        fd[2]=s;fi[2]=r;
    }
}

// ---------- CSR build ----------
__global__ void k_deg(const int* __restrict__ ei, int E, int n, int* __restrict__ deg) {
    int i = blockIdx.x * blockDim.x + threadIdx.x;
    if (i >= E + n) return;
    int d = (i < E) ? ei[E + i] : i - E;
    atomicAdd(&deg[d], 1);
}

__global__ void k_chunksum(const int* __restrict__ deg, int* __restrict__ bsum, int n) {
    int t = threadIdx.x;
    int i = blockIdx.x * 256 + t;
    int v = (i < n) ? deg[i] : 0;
#pragma unroll
    for (int o = 1; o < 64; o <<= 1) v += __shfl_xor(v, o);
    __shared__ int wsum[4];
    if ((t & 63) == 0) wsum[t >> 6] = v;
    __syncthreads();
    if (t == 0) bsum[blockIdx.x] = wsum[0] + wsum[1] + wsum[2] + wsum[3];
}

__global__ void k_scan_small(int* __restrict__ a, int nb) {
    __shared__ int buf[256];
    int t = threadIdx.x;
    int v = (t < nb) ? a[t] : 0;
    buf[t] = v;
    __syncthreads();
    for (int o = 1; o < 256; o <<= 1) {
        int add = (t >= o) ? buf[t - o] : 0;
        __syncthreads();
        buf[t] += add;
        __syncthreads();
    }
    if (t < nb) a[t] = buf[t] - v;
    if (t == 0) a[nb] = buf[nb - 1];
}

__global__ void k_scan_apply(const int* __restrict__ deg, const int* __restrict__ bsum,
                             int* __restrict__ off, int* __restrict__ cur, int n) {
    __shared__ int buf[256];
    int b = blockIdx.x, t = threadIdx.x;
    int i = b * 256 + t;
    int v = (i < n) ? deg[i] : 0;
    buf[t] = v;
    __syncthreads();
    for (int o = 1; o < 256; o <<= 1) {
        int add = (t >= o) ? buf[t - o] : 0;
        __syncthreads();
        buf[t] += add;
        __syncthreads();
    }
    int excl = bsum[b] + buf[t] - v;
    if (i < n) { off[i] = excl; cur[i] = excl; }
    if (b == 0 && t == 0) off[n] = bsum[gridDim.x];
}

__global__ void k_scatter(const int* __restrict__ ei, int E, int n,
                          int* __restrict__ cursor, int* __restrict__ csr) {
    int i = blockIdx.x * blockDim.x + threadIdx.x;
    if (i >= E + n) return;
    int s, d;
    if (i < E) { s = ei[i]; d = ei[E + i]; } else { s = d = i - E; }
    int pos = atomicAdd(&cursor[d], 1);
    csr[pos] = s;
}

// ---------- linear: 4 nodes per block (128 thr), W reads shared ----------
__global__ __launch_bounds__(128) void k_linear(
    const float* __restrict__ x, const float* __restrict__ W,
    const float* __restrict__ a_src, const float* __restrict__ a_dst,
    float* __restrict__ h, float* __restrict__ es, float* __restrict__ ed,
    int d_in, int n) {
    int n0 = blockIdx.x * 4;
    int t = threadIdx.x;
    int w = t >> 6, lane = t & 63;
    __shared__ float xs[4][HID];
    __shared__ float p1[2], p2[2];
#pragma unroll
    for (int u = 0; u < 4; ++u) {
        int node = n0 + u;
        if (t < d_in) xs[u][t] = (node < n) ? x[(size_t)node * d_in + t] : 0.f;
    }
    __syncthreads();
    float acc[4] = {0.f, 0.f, 0.f, 0.f};
    for (int k = 0; k < d_in; ++k) {
        float wv = W[k * HID + t];
#pragma unroll
        for (int u = 0; u < 4; ++u) acc[u] += xs[u][k] * wv;
    }
    float asv = a_src[t], adv = a_dst[t];
    for (int u = 0; u < 4; ++u) {
        int node = n0 + u;
        if (node >= n) break;                     // uniform across block
        h[(size_t)node * HID + t] = acc[u];
        float v1 = acc[u] * asv, v2 = acc[u] * adv;
#pragma unroll
        for (int o = 32; o > 0; o >>= 1) { v1 += __shfl_xor(v1, o); v2 += __shfl_xor(v2, o); }
        if (lane == 0) { p1[w] = v1; p2[w] = v2; }
        __syncthreads();
        if (t == 0) { es[node] = p1[0] + p1[1]; ed[node] = p2[0] + p2[1]; }
        __syncthreads();
    }
}

// ---------- fused GAT aggregation over CSR (wave per dst node) ----------
__global__ __launch_bounds__(256) void k_gat_csr(
    const int* __restrict__ off, const int* __restrict__ csr,
    const float* __restrict__ es, const float* __restrict__ ed,
    const float* __restrict__ h, const float* __restrict__ b,
    float* __restrict__ agg, int n,
    _Float16* __restrict__ h16, float* __restrict__ n2) {
    int node = blockIdx.x * 4 + (threadIdx.x >> 6);
    int lane = threadIdx.x & 63;
    if (node >= n) return;                        // wave-uniform
    int beg = off[node], end = off[node + 1];
    float edd = ed[node];
    float m = -INFINITY;
    for (int j = beg + lane; j < end; j += 64) {
        int s = csr[j];
        float e = es[s] + edd;
        e = e > 0.f ? e : NEG_SLOPE * e;
        m = fmaxf(m, e);
    }
#pragma unroll
    for (int o = 32; o > 0; o >>= 1) m = fmaxf(m, __shfl_xor(m, o));
    float den = 0.f, a0 = 0.f, a1 = 0.f;
    int j = beg;
    for (; j + 1 < end; j += 2) {
        int s0 = csr[j], s1 = csr[j + 1];
        float e0 = es[s0] + edd;
        float e1 = es[s1] + edd;
        e0 = e0 > 0.f ? e0 : NEG_SLOPE * e0;
        e1 = e1 > 0.f ? e1 : NEG_SLOPE * e1;
        float ex0 = expf(e0 - m);
        float ex1 = expf(e1 - m);
        float h00 = h[(size_t)s0 * HID + lane];
        float h01 = h[(size_t)s0 * HID + 64 + lane];
        float h10 = h[(size_t)s1 * HID + lane];
        float h11 = h[(size_t)s1 * HID + 64 + lane];
        den += ex0 + ex1;
        a0 += ex0 * h00 + ex1 * h10;
        a1 += ex0 * h01 + ex1 * h11;
    }
    if (j < end) {
        int s0 = csr[j];
        float e0 = es[s0] + edd;
        e0 = e0 > 0.f ? e0 : NEG_SLOPE * e0;
        float ex0 = expf(e0 - m);
        den += ex0;
        a0 += ex0 * h[(size_t)s0 * HID + lane];
        a1 += ex0 * h[(size_t)s0 * HID + 64 + lane];
    }
    float inv = 1.f / fmaxf(den, 1e-16f);
    float v0 = a0 * inv + b[lane];
    float v1 = a1 * inv + b[64 + lane];
    float r0 = v0 > 0.f ? v0 : 0.f;
    float r1 = v1 > 0.f ? v1 : 0.f;
    agg[(size_t)node * HID + lane] = r0;
    agg[(size_t)node * HID + 64 + lane] = r1;
    if (h16) {
        h16[(size_t)node * HID + lane] = (_Float16)r0;
        h16[(size_t)node * HID + 64 + lane] = (_Float16)r1;
    }
    if (n2) {
        float s2 = r0 * r0 + r1 * r1;
#pragma unroll
        for (int o = 32; o > 0; o >>= 1) s2 += __shfl_xor(s2, o);
        if (lane == 0) n2[node] = s2;
    }
}

// ---------- MFMA KNN scan ----------
// grid (79, CSPLIT=8) = 632 blocks (~2.5/CU co-resident) for latency hiding.
// Per chunk: hoisted nr2 prefetch, branch-free full-chunk fast path,
// top-3 per (row-class, split).
__global__ __launch_bounds__(256) void k_knn_scan(
    const _Float16* __restrict__ hr2, const _Float16* __restrict__ hc2,
    const float* __restrict__ nr2, int n_c, int n_r, int rs_chunk,
    int* __restrict__ cand_i) {
    __shared__ _Float16 lds[2][64 * HID];
    int t = threadIdx.x, w = t >> 6, lane = t & 63;
    int li = lane & 15, q = lane >> 4;
    int c0 = blockIdx.x * KNN_CB;
    int split = blockIdx.y;
    int rbeg = split * rs_chunk;
    int rows = min(rs_chunk, n_r - rbeg);
    int rend = rbeg + rows;

    if (rows <= 0) {
        int c = c0 + w * 16 + li;
        if (c < n_c) {
            size_t base = ((size_t)(c * CSPLIT + split) * 4 + q) * 3;
            for (int k = 0; k < 3; ++k) cand_i[base + k] = 0x7fffffff;
        }
        return;
    }

    // B fragments: collider col = li, k = ks*32 + q*8 .. +7
    f16x8 bf[4];
    {
        int c = c0 + w * 16 + li;
        int cc = min(c, n_c - 1);
#pragma unroll
        for (int ks = 0; ks < 4; ++ks)
            bf[ks] = *(const f16x8*)(hc2 + (size_t)cc * HID + ks * 32 + q * 8);
    }

    float bd[3]; int bi[3];
#pragma unroll
    for (int k = 0; k < 3; ++k) { bd[k] = INFINITY; bi[k] = 0x7fffffff; }

    int nch = (rows + 63) >> 6;

    auto STAGE = [&](int bsel, int R) {
#pragma unroll
        for (int j = 0; j < 4; ++j) {
            int row = w * 16 + j * 4 + q;
            int gr = min(R + row, n_r - 1);
            int sslot = li ^ (row & 7);
            const _Float16* src = hr2 + (size_t)gr * HID + sslot * 8;
            _Float16* dst = &lds[bsel][(w * 16 + j * 4) * HID];  // wave-uniform
            __builtin_amdgcn_global_load_lds(
                (const __attribute__((address_space(1))) void*)src,
                (__attribute__((address_space(3))) void*)dst, 16, 0, 0);
        }
    };

    STAGE(0, rbeg);
    __syncthreads();

    for (int ch = 0; ch < nch; ++ch) {
        int cur = ch & 1;
        if (ch + 1 < nch) STAGE(cur ^ 1, rbeg + (ch + 1) * 64);  // prefetch
        int R = rbeg + ch * 64;
        const _Float16* buf = lds[cur];
        int sw = li & 7;
        if (R + 64 <= rend) {
            // fast path: hoisted nr2 loads, no per-tt branches
            float4 nrv[4];
#pragma unroll
            for (int tt = 0; tt < 4; ++tt)
                nrv[tt] = *(const float4*)(nr2 + R + tt * 16 + q * 4);
#pragma unroll
            for (int tt = 0; tt < 4; ++tt) {
                f32x4 a0 = {0.f, 0.f, 0.f, 0.f};
                int lr = tt * 16 + li;
                int swr = lr & 7;
#pragma unroll
                for (int ks = 0; ks < 4; ++ks) {
                    f16x8 af = *(const f16x8*)(&buf[lr * HID + (((ks * 4 + q) ^ swr) << 3)]);
                    a0 = __builtin_amdgcn_mfma_f32_16x16x32_f16(af, bf[ks], a0, 0, 0, 0);
                }
                int r_base = R + tt * 16 + q * 4;
                float sv[4] = {nrv[tt].x, nrv[tt].y, nrv[tt].z, nrv[tt].w};
#pragma unroll
                for (int i = 0; i < 4; ++i)
                    ins3(sv[i] - 2.f * a0[i], r_base + i, bd, bi);
            }
        } else {
            int rows_rem = rend - R;
#pragma unroll
            for (int tt = 0; tt < 4; ++tt) {
                int br = tt * 16;
                if (br < rows_rem) {
                    f32x4 a0 = {0.f, 0.f, 0.f, 0.f};
                    int lr = br + li;
                    int swr = lr & 7;
#pragma unroll
                    for (int ks = 0; ks < 4; ++ks) {
                        f16x8 af = *(const f16x8*)(&buf[lr * HID + (((ks * 4 + q) ^ swr) << 3)]);
                        a0 = __builtin_amdgcn_mfma_f32_16x16x32_f16(af, bf[ks], a0, 0, 0, 0);
                    }
                    int r_base = R + br + q * 4;
                    float4 nrv = *(const float4*)(nr2 + r_base);
                    float sv[4] = {nrv.x, nrv.y, nrv.z, nrv.w};
#pragma unroll
                    for (int i = 0; i < 4; ++i) {
                        int r = r_base + i;
                        if (r < rend) ins3(sv[i] - 2.f * a0[i], r, bd, bi);
                    }
                }
            }
        }
        (void)sw;
        __syncthreads();
    }

    {
        int c = c0 + w * 16 + li;
        if (c < n_c) {
            size_t base = ((size_t)(c * CSPLIT + split) * 4 + q) * 3;
#pragma unroll
            for (int k = 0; k < 3; ++k) cand_i[base + k] = bi[k];
        }
    }
}

// ---------- exact rerank + pooling: block per collider, coalesced, high MLP --
// 96 cands; thread t owns (j = p*8 + t/32, k4 = t%32) for p = 0..11 — all 12
// row-loads issued as an independent batch. launch_bounds(256,4) keeps VGPR
// budget at 128 so the batch stays in flight.
__global__ __launch_bounds__(256, 4) void k_rerank(
    const int* __restrict__ cand_i, const float* __restrict__ hc,
    const float* __restrict__ hr, const float* __restrict__ nr2,
    int n_r, float* __restrict__ pooled, float* __restrict__ cnt) {
    int c = blockIdx.x;
    int t = threadIdx.x;
    __shared__ float hcs[HID];
    __shared__ int ci[NCAND];
    __shared__ float sc[NCAND];
    __shared__ int scr[NCAND];
    __shared__ int bidx[3];
    if (t < HID) hcs[t] = hc[(size_t)c * HID + t];
    if (t < NCAND) {
        int r = cand_i[(size_t)c * NCAND + t];
        ci[t] = ((unsigned)r < (unsigned)n_r) ? r : -1;
    }
    __syncthreads();

    int k4 = t & 31;
    int g = t >> 5;                                // 0..7
    const float4* hr4 = (const float4*)hr;
    float4 a = ((const float4*)hcs)[k4];

    int rj[12];
    float4 v[12];
#pragma unroll
    for (int p = 0; p < 12; ++p) {                 // issue all loads (MLP)
        rj[p] = ci[p * 8 + g];
        v[p] = hr4[(size_t)max(rj[p], 0) * 32 + k4];
    }
    float fd[3] = {INFINITY, INFINITY, INFINITY};
    int fi[3] = {0x7fffffff, 0x7fffffff, 0x7fffffff};
#pragma unroll
    for (int p = 0; p < 12; ++p) {
        float d = a.x * v[p].x + a.y * v[p].y + a.z * v[p].z + a.w * v[p].w;
#pragma unroll
        for (int o = 1; o < 32; o <<= 1) d += __shfl_xor(d, o);
        if (k4 == 0) {
            int j = p * 8 + g;
            sc[j] = (rj[p] >= 0) ? nr2[rj[p]] - 2.f * d : INFINITY;
            scr[j] = (rj[p] >= 0) ? rj[p] : 0x7fffffff;
        }
    }
    __syncthreads();
    if (t < 64) {
        ins3(sc[t], scr[t], fd, fi);
        if (t < 32) ins3(sc[64 + t], scr[64 + t], fd, fi);
#pragma unroll
        for (int o = 1; o < 64; o <<= 1) {
            float sd0 = __shfl_xor(fd[0], o), sd1 = __shfl_xor(fd[1], o), sd2 = __shfl_xor(fd[2], o);
            int si0 = __shfl_xor(fi[0], o), si1 = __shfl_xor(fi[1], o), si2 = __shfl_xor(fi[2], o);
            ins3(sd0, si0, fd, fi);
            ins3(sd1, si1, fd, fi);
            ins3(sd2, si2, fd, fi);
        }
        if (t == 0) { bidx[0] = fi[0]; bidx[1] = fi[1]; bidx[2] = fi[2]; }
    }
    __syncthreads();
    if (t < HID) {
        float hv = hcs[t];
#pragma unroll
        for (int qq = 0; qq < 3; ++qq) {
            int b = bidx[qq];
            if (b >= 0 && b < n_r) {
                atomicAdd(&pooled[(size_t)b * HID + t], hv);
                if (t == 0) atomicAdd(&cnt[b], 1.0f);
            }
        }
    }
}

// one wave per resting node
__global__ void k_decode(const float* __restrict__ hr, const float* __restrict__ pooled,
                         const float* __restrict__ cnt, const float* __restrict__ Wd,
                         const float* __restrict__ bd, float* __restrict__ out, int n) {
    int node = blockIdx.x * (blockDim.x / 64) + (threadIdx.x >> 6);
    int lane = threadIdx.x & 63;
    if (node >= n) return;
    float c = fmaxf(cnt[node], 1.0f);
    float a0 = 0.f, a1 = 0.f, a2 = 0.f;
    for (int k = lane; k < HID; k += 64) {
        float v = hr[(long long)node * HID + k];
        a0 += v * Wd[k * 3 + 0];
        a1 += v * Wd[k * 3 + 1];
        a2 += v * Wd[k * 3 + 2];
        float p = pooled[(long long)node * HID + k] / c;
        a0 += p * Wd[(HID + k) * 3 + 0];
        a1 += p * Wd[(HID + k) * 3 + 1];
        a2 += p * Wd[(HID + k) * 3 + 2];
    }
    for (int off = 32; off > 0; off >>= 1) {
        a0 += __shfl_down(a0, off);
        a1 += __shfl_down(a1, off);
        a2 += __shfl_down(a2, off);
    }
    if (lane == 0) {
        out[(long long)node * 3 + 0] = a0 + bd[0];
        out[(long long)node * 3 + 1] = a1 + bd[1];
        out[(long long)node * 3 + 2] = a2 + bd[2];
    }
}

// ---------- launch ----------
static inline int cdiv(long long a, int b) { return (int)((a + b - 1) / b); }

extern "C" void kernel_launch(void* const* d_in, const int* in_sizes, int n_in,
                              void* d_out, int out_size, void* d_ws, size_t ws_size,
                              hipStream_t stream) {
    const float* x_r = (const float*)d_in[0];
    const float* x_c = (const float*)d_in[1];
    const int* ei_r = (const int*)d_in[2];
    const int* ei_c = (const int*)d_in[3];
    const float* W_r1 = (const float*)d_in[5];
    const float* as_r1 = (const float*)d_in[6];
    const float* ad_r1 = (const float*)d_in[7];
    const float* b_r1 = (const float*)d_in[8];
    const float* W_r2 = (const float*)d_in[9];
    const float* as_r2 = (const float*)d_in[10];
    const float* ad_r2 = (const float*)d_in[11];
    const float* b_r2 = (const float*)d_in[12];
    const float* W_c1 = (const float*)d_in[13];
    const float* as_c1 = (const float*)d_in[14];
    const float* ad_c1 = (const float*)d_in[15];
    const float* b_c1 = (const float*)d_in[16];
    const float* W_c2 = (const float*)d_in[17];
    const float* as_c2 = (const float*)d_in[18];
    const float* ad_c2 = (const float*)d_in[19];
    const float* b_c2 = (const float*)d_in[20];
    const float* W_dec = (const float*)d_in[21];
    const float* b_dec = (const float*)d_in[22];
    float* out = (float*)d_out;

    const int N_R = in_sizes[0] / 6;
    const int N_C = in_sizes[1] / 6;
    const int E_R = in_sizes[2] / 2;
    const int E_C = in_sizes[3] / 2;

    float* ws = (float*)d_ws;
    size_t off = 0;
    auto alloc = [&](size_t nf) {
        float* p = ws + off;
        off += (nf + 3) & ~(size_t)3;
        return p;
    };
    float* r_h    = alloc((size_t)N_R * HID);
    float* r_agg  = alloc((size_t)N_R * HID);
    float* c_h    = alloc((size_t)N_C * HID);
    float* c_agg  = alloc((size_t)N_C * HID);
    float* pooled = alloc((size_t)N_R * HID);
    float* r_es = alloc(N_R);
    float* r_ed = alloc(N_R);
    float* c_es = alloc(N_C);
    float* c_ed = alloc(N_C);
    float* cnt = alloc(N_R);
    float* nr2 = alloc((size_t)N_R + 512);
    _Float16* hr2 = (_Float16*)alloc((size_t)N_R * HID / 2);
    _Float16* hc2 = (_Float16*)alloc((size_t)N_C * HID / 2);
    int* cand_i = (int*)alloc((size_t)N_C * NCAND);
    // CSR (resting)
    int* r_deg = (int*)alloc(N_R);
    int* r_off = (int*)alloc((size_t)N_R + 1);
    int* r_cur = (int*)alloc(N_R);
    int* r_csr = (int*)alloc((size_t)E_R + N_R);
    int* r_bsum = (int*)alloc(256);
    // CSR (collider)
    int* c_deg = (int*)alloc(N_C);
    int* c_off = (int*)alloc((size_t)N_C + 1);
    int* c_cur = (int*)alloc(N_C);
    int* c_csr = (int*)alloc((size_t)E_C + N_C);
    int* c_bsum = (int*)alloc(256);
    (void)ws_size; (void)n_in; (void)out_size;

    auto build_csr = [&](const int* ei, int E, int n, int* deg, int* offp, int* cur,
                         int* csr, int* bsum) {
        hipMemsetAsync(deg, 0, (size_t)n * sizeof(int), stream);
        k_deg<<<cdiv(E + n, 256), 256, 0, stream>>>(ei, E, n, deg);
        int nb = cdiv(n, 256);
        k_chunksum<<<nb, 256, 0, stream>>>(deg, bsum, n);
        k_scan_small<<<1, 256, 0, stream>>>(bsum, nb);
        k_scan_apply<<<nb, 256, 0, stream>>>(deg, bsum, offp, cur, n);
        k_scatter<<<cdiv(E + n, 256), 256, 0, stream>>>(ei, E, n, cur, csr);
    };
    auto gat = [&](const float* x, int d_in_dim, int n, const int* offp, const int* csr,
                   const float* W, const float* as_, const float* ad_, const float* b,
                   float* h, float* es, float* ed, float* agg,
                   _Float16* h16, float* n2) {
        k_linear<<<cdiv(n, 4), 128, 0, stream>>>(x, W, as_, ad_, h, es, ed, d_in_dim, n);
        k_gat_csr<<<cdiv(n, 4), 256, 0, stream>>>(offp, csr, es, ed, h, b, agg, n, h16, n2);
    };

    // resting branch
    build_csr(ei_r, E_R, N_R, r_deg, r_off, r_cur, r_csr, r_bsum);
    gat(x_r, 6, N_R, r_off, r_csr, W_r1, as_r1, ad_r1, b_r1, r_h, r_es, r_ed, r_agg,
        nullptr, nullptr);
    gat(r_agg, HID, N_R, r_off, r_csr, W_r2, as_r2, ad_r2, b_r2, r_h, r_es, r_ed, r_agg,
        hr2, nr2);
    // collider branch
    build_csr(ei_c, E_C, N_C, c_deg, c_off, c_cur, c_csr, c_bsum);
    gat(x_c, 6, N_C, c_off, c_csr, W_c1, as_c1, ad_c1, b_c1, c_h, c_es, c_ed, c_agg,
        nullptr, nullptr);
    gat(c_agg, HID, N_C, c_off, c_csr, W_c2, as_c2, ad_c2, b_c2, c_h, c_es, c_ed, c_agg,
        hc2, nullptr);

    // KNN pooling buffers
    hipMemsetAsync(pooled, 0, (size_t)N_R * HID * sizeof(float), stream);
    hipMemsetAsync(cnt, 0, (size_t)N_R * sizeof(float), stream);

    // MFMA candidate scan
    int RS = cdiv(N_R, CSPLIT * 64) * 64;
    dim3 sgrid(cdiv(N_C, KNN_CB), CSPLIT);
    k_knn_scan<<<sgrid, 256, 0, stream>>>(hr2, hc2, nr2, N_C, N_R, RS, cand_i);

    // exact rerank + pooling
    k_rerank<<<N_C, 256, 0, stream>>>(cand_i, c_agg, r_agg, nr2, N_R, pooled, cnt);

    // decode
    k_decode<<<cdiv(N_R, 4), 256, 0, stream>>>(r_agg, pooled, cnt, W_dec, b_dec, out, N_R);
}